// Round 2
// baseline (2670.474 us; speedup 1.0000x reference)
//
#include <hip/hip_runtime.h>

#define NATOMS 30000
#define NPAD   30080        // 235*128
#define NEDGE  60000
#define HDIM   768
#define H4     192
#define NG     600
#define GPAD   640          // 5*128
#define LSEQ   20
#define BNEPS  1e-5f

typedef __attribute__((ext_vector_type(8))) short bf16x8;
typedef __attribute__((ext_vector_type(4))) float f32x4;

__device__ __forceinline__ ushort f2bf(float f) {
    union { float f; unsigned u; } v; v.f = f;
    unsigned r = v.u + 0x7FFFu + ((v.u >> 16) & 1u);
    return (ushort)(r >> 16);
}
__device__ __forceinline__ float bf2f(ushort u) {
    union { unsigned u; float f; } v; v.u = ((unsigned)u) << 16; return v.f;
}
__device__ __forceinline__ ushort4 pack4(float4 v) {
    ushort4 r; r.x = f2bf(v.x); r.y = f2bf(v.y); r.z = f2bf(v.z); r.w = f2bf(v.w); return r;
}
__device__ __forceinline__ float4 unpack4(ushort4 u) {
    float4 r; r.x = bf2f(u.x); r.y = bf2f(u.y); r.z = bf2f(u.z); r.w = bf2f(u.w); return r;
}

// ---------- input MLP: h0 = BN(relu(x@Win+bin)); TOTAL=bf16(h0); HB=bf16(h0); zero HB pad rows ----------
__global__ __launch_bounds__(256) void mlp_in_k(
    const float* __restrict__ x, const float* __restrict__ Win, const float* __restrict__ bin,
    const float* __restrict__ g, const float* __restrict__ b,
    const float* __restrict__ m, const float* __restrict__ vv,
    ushort* __restrict__ TOTAL, ushort* __restrict__ HB)
{
    __shared__ float xs[8][64];
    int r0 = blockIdx.x * 8;
    for (int i = threadIdx.x; i < 8 * 64; i += 256) {
        int rr = i >> 6, kk = i & 63;
        int row = r0 + rr;
        xs[rr][kk] = (row < NATOMS) ? x[(size_t)row * 64 + kk] : 0.f;
    }
    __syncthreads();
    for (int c = threadIdx.x; c < HDIM; c += 256) {
        float s = g[c] * rsqrtf(vv[c] + BNEPS);
        float mm = m[c], bb = b[c];
        float acc[8];
        #pragma unroll
        for (int rr = 0; rr < 8; rr++) acc[rr] = bin[c];
        for (int k = 0; k < 64; k++) {
            float w = Win[k * HDIM + c];
            #pragma unroll
            for (int rr = 0; rr < 8; rr++) acc[rr] += xs[rr][k] * w;
        }
        #pragma unroll
        for (int rr = 0; rr < 8; rr++) {
            int row = r0 + rr;
            if (row < NATOMS) {
                float hv = (fmaxf(acc[rr], 0.f) - mm) * s + bb;
                ushort hb = f2bf(hv);
                TOTAL[(size_t)row * HDIM + c] = hb;
                HB[(size_t)row * HDIM + c] = hb;
            } else if (row < NPAD) {
                HB[(size_t)row * HDIM + c] = 0;
            }
        }
    }
}

// ---------- transpose + cast: W[K][Nsrc] f32 -> WT[Npad][K] bf16 (pad rows zero) ----------
__global__ void transpose_cast_k(const float* __restrict__ W, ushort* __restrict__ WT,
                                 int K, int Nsrc, int Npad)
{
    int idx = blockIdx.x * 256 + threadIdx.x;   // over Npad*K
    if (idx >= Npad * K) return;
    int n = idx / K, k = idx - n * K;
    float v = (n < Nsrc) ? W[(size_t)k * Nsrc + n] : 0.f;
    WT[idx] = f2bf(v);
}

// ---------- bf16 MFMA GEMM: C = A[Mpad][K] @ Bt[Npad][K]^T, fused epilogues ----------
// EPI: 0 = none, 1 = bias+relu+BN, 2 = bias+tanh, 3 = bias
template <int EPI>
__global__ __launch_bounds__(256) void gemm_bt(
    const ushort* __restrict__ A, const ushort* __restrict__ Bt,
    float* __restrict__ Cf, ushort* __restrict__ Cb,
    const float* __restrict__ bias,
    const float* __restrict__ bng, const float* __restrict__ bnb,
    const float* __restrict__ bnm, const float* __restrict__ bnv,
    int Mreal, int Nreal, int K)
{
    __shared__ ushort Ash[128 * 40];
    __shared__ ushort Bsh[128 * 40];
    int t = threadIdx.x;
    int lane = t & 63, wave = t >> 6;
    int wr = wave >> 1, wc = wave & 1;
    int brow = blockIdx.x, bcol = blockIdx.y;

    f32x4 acc[4][4];
    #pragma unroll
    for (int i = 0; i < 4; i++)
        #pragma unroll
        for (int j = 0; j < 4; j++) acc[i][j] = (f32x4)0.f;

    const int r = t >> 1, half = t & 1;
    const ushort* Ag = A + (size_t)(brow * 128 + r) * K + half * 16;
    const ushort* Bg = Bt + (size_t)(bcol * 128 + r) * K + half * 16;
    const int lr = lane & 15, lk = (lane >> 4) * 8;

    for (int kt = 0; kt < K; kt += 32) {
        uint4 a0 = *(const uint4*)(Ag + kt);
        uint4 a1 = *(const uint4*)(Ag + kt + 8);
        uint4 b0 = *(const uint4*)(Bg + kt);
        uint4 b1 = *(const uint4*)(Bg + kt + 8);
        *(uint4*)(&Ash[r * 40 + half * 16]) = a0;
        *(uint4*)(&Ash[r * 40 + half * 16 + 8]) = a1;
        *(uint4*)(&Bsh[r * 40 + half * 16]) = b0;
        *(uint4*)(&Bsh[r * 40 + half * 16 + 8]) = b1;
        __syncthreads();

        bf16x8 af[4], bfr[4];
        #pragma unroll
        for (int mf = 0; mf < 4; mf++)
            af[mf] = *(const bf16x8*)(&Ash[(wr * 64 + mf * 16 + lr) * 40 + lk]);
        #pragma unroll
        for (int nf = 0; nf < 4; nf++)
            bfr[nf] = *(const bf16x8*)(&Bsh[(wc * 64 + nf * 16 + lr) * 40 + lk]);
        #pragma unroll
        for (int mf = 0; mf < 4; mf++)
            #pragma unroll
            for (int nf = 0; nf < 4; nf++)
                acc[mf][nf] = __builtin_amdgcn_mfma_f32_16x16x32_bf16(af[mf], bfr[nf], acc[mf][nf], 0, 0, 0);
        __syncthreads();
    }

    const int lq = lane >> 4;
    #pragma unroll
    for (int mf = 0; mf < 4; mf++) {
        #pragma unroll
        for (int nf = 0; nf < 4; nf++) {
            int col = bcol * 128 + wc * 64 + nf * 16 + lr;
            #pragma unroll
            for (int rg = 0; rg < 4; rg++) {
                int row = brow * 128 + wr * 64 + mf * 16 + lq * 4 + rg;
                if (row < Mreal && col < Nreal) {
                    float v = acc[mf][nf][rg];
                    if (EPI >= 1) v += bias[col];
                    if (EPI == 1) {
                        v = fmaxf(v, 0.f);
                        float s = bng[col] * rsqrtf(bnv[col] + BNEPS);
                        v = (v - bnm[col]) * s + bnb[col];
                    } else if (EPI == 2) {
                        v = tanhf(v);
                    }
                    size_t o = (size_t)row * Nreal + col;
                    if (Cf) Cf[o] = v;
                    if (Cb) Cb[o] = f2bf(v);
                }
            }
        }
    }
}

// ---------- self-loop messages: AGG[i] = relu(P[i] + bc)  (P is bf16) ----------
__global__ void selfloop_k(const ushort* __restrict__ P, const float* __restrict__ bc,
                           float* __restrict__ AGG)
{
    size_t idx = (size_t)blockIdx.x * 256 + threadIdx.x;   // over NATOMS*H4
    int c4 = (int)(idx % H4);
    float4 p = unpack4(((const ushort4*)P)[idx]);
    float4 bb = ((const float4*)bc)[c4];
    float4 v;
    v.x = fmaxf(p.x + bb.x, 0.f); v.y = fmaxf(p.y + bb.y, 0.f);
    v.z = fmaxf(p.z + bb.z, 0.f); v.w = fmaxf(p.w + bb.w, 0.f);
    ((float4*)AGG)[idx] = v;
}

// ---------- edge messages: AGG[dst] += relu(P[src] + ea@Wce + bc) ----------
__global__ __launch_bounds__(192) void edge_k(
    const ushort* __restrict__ P, const int* __restrict__ src_a, const int* __restrict__ dst_a,
    const float* __restrict__ ea, const float* __restrict__ Wce, const float* __restrict__ bc,
    float* __restrict__ AGG)
{
    int e = blockIdx.x;
    int s = src_a[e], d = dst_a[e];
    float e0 = ea[e * 6 + 0], e1 = ea[e * 6 + 1], e2 = ea[e * 6 + 2];
    float e3 = ea[e * 6 + 3], e4 = ea[e * 6 + 4], e5 = ea[e * 6 + 5];
    int c4 = threadIdx.x;
    const ushort4* P4 = (const ushort4*)(P + (size_t)s * HDIM);
    const float4* W4 = (const float4*)Wce;
    const float4* b4 = (const float4*)bc;
    float4 p = unpack4(P4[c4]);
    float4 w0 = W4[0 * H4 + c4], w1 = W4[1 * H4 + c4], w2 = W4[2 * H4 + c4];
    float4 w3 = W4[3 * H4 + c4], w4 = W4[4 * H4 + c4], w5 = W4[5 * H4 + c4];
    float4 bb = b4[c4];
    float4 v;
    v.x = fmaxf(p.x + e0 * w0.x + e1 * w1.x + e2 * w2.x + e3 * w3.x + e4 * w4.x + e5 * w5.x + bb.x, 0.f);
    v.y = fmaxf(p.y + e0 * w0.y + e1 * w1.y + e2 * w2.y + e3 * w3.y + e4 * w4.y + e5 * w5.y + bb.y, 0.f);
    v.z = fmaxf(p.z + e0 * w0.z + e1 * w1.z + e2 * w2.z + e3 * w3.z + e4 * w4.z + e5 * w5.z + bb.z, 0.f);
    v.w = fmaxf(p.w + e0 * w0.w + e1 * w1.w + e2 * w2.w + e3 * w3.w + e4 * w4.w + e5 * w5.w + bb.w, 0.f);
    float* Ar = AGG + (size_t)d * HDIM + c4 * 4;
    atomicAdd(Ar + 0, v.x); atomicAdd(Ar + 1, v.y);
    atomicAdd(Ar + 2, v.z); atomicAdd(Ar + 3, v.w);
}

// ---------- h = BN(agg); TOTAL(bf16) += h; HB = bf16(h) ----------
__global__ void bn_total_k(const float* __restrict__ AGG,
    const float* __restrict__ g, const float* __restrict__ b,
    const float* __restrict__ m, const float* __restrict__ vv,
    ushort* __restrict__ TOTAL, ushort* __restrict__ HB)
{
    size_t idx = (size_t)blockIdx.x * 256 + threadIdx.x;   // over NATOMS*H4
    int c4 = (int)(idx % H4);
    float4 a = ((const float4*)AGG)[idx];
    float4 gg = ((const float4*)g)[c4], bb = ((const float4*)b)[c4];
    float4 mm = ((const float4*)m)[c4], vq = ((const float4*)vv)[c4];
    float4 hv;
    hv.x = (a.x - mm.x) * (gg.x * rsqrtf(vq.x + BNEPS)) + bb.x;
    hv.y = (a.y - mm.y) * (gg.y * rsqrtf(vq.y + BNEPS)) + bb.y;
    hv.z = (a.z - mm.z) * (gg.z * rsqrtf(vq.z + BNEPS)) + bb.z;
    hv.w = (a.w - mm.w) * (gg.w * rsqrtf(vq.w + BNEPS)) + bb.w;
    float4 tt = unpack4(((const ushort4*)TOTAL)[idx]);
    tt.x += hv.x; tt.y += hv.y; tt.z += hv.z; tt.w += hv.w;
    ((ushort4*)TOTAL)[idx] = pack4(tt);
    ((ushort4*)HB)[idx] = pack4(hv);
}

// ---------- per-graph pooling -> COMB bf16 [GPAD][2304] = [mean | add | max] ----------
__global__ __launch_bounds__(192) void pool_k(const ushort* __restrict__ TOTAL,
                                              const int* __restrict__ bidx,
                                              ushort* __restrict__ COMB)
{
    int g = blockIdx.x;
    int c4 = threadIdx.x;
    ushort4* C4 = (ushort4*)COMB;
    if (g >= NG) {
        ushort4 z; z.x = z.y = z.z = z.w = 0;
        C4[(size_t)g * 576 + c4] = z;
        C4[(size_t)g * 576 + 192 + c4] = z;
        C4[(size_t)g * 576 + 384 + c4] = z;
        return;
    }
    int lo, hi;
    { int a = 0, b = NATOMS; while (a < b) { int mid = (a + b) >> 1; if (bidx[mid] < g) a = mid + 1; else b = mid; } lo = a; }
    { int a = lo, b = NATOMS; while (a < b) { int mid = (a + b) >> 1; if (bidx[mid] <= g) a = mid + 1; else b = mid; } hi = a; }
    int cnt = hi - lo;
    float4 sum = {0.f, 0.f, 0.f, 0.f};
    float4 mx = {-INFINITY, -INFINITY, -INFINITY, -INFINITY};
    for (int r = lo; r < hi; r++) {
        float4 v = unpack4(((const ushort4*)TOTAL)[(size_t)r * H4 + c4]);
        sum.x += v.x; sum.y += v.y; sum.z += v.z; sum.w += v.w;
        mx.x = fmaxf(mx.x, v.x); mx.y = fmaxf(mx.y, v.y);
        mx.z = fmaxf(mx.z, v.z); mx.w = fmaxf(mx.w, v.w);
    }
    float inv = 1.f / fmaxf((float)cnt, 1.f);
    if (cnt == 0) { mx.x = mx.y = mx.z = mx.w = 0.f; }
    float4 mean = {sum.x * inv, sum.y * inv, sum.z * inv, sum.w * inv};
    C4[(size_t)g * 576 + c4] = pack4(mean);
    C4[(size_t)g * 576 + 192 + c4] = pack4(sum);
    C4[(size_t)g * 576 + 384 + c4] = pack4(mx);
}

// ---------- last_hidden broadcast: out0[g][l][c] = HS[g][c] ----------
__global__ void bcast_k(const float* __restrict__ HS, float* __restrict__ out0)
{
    size_t idx = (size_t)blockIdx.x * 256 + threadIdx.x;   // over NG*LSEQ*H4
    int c4 = (int)(idx % H4);
    int g = (int)(idx / ((size_t)H4 * LSEQ));
    ((float4*)out0)[idx] = ((const float4*)HS)[(size_t)g * H4 + c4];
}

// ---------- recon gather: out2[n] = RECONG[bidx[n]] ----------
__global__ void recon_k(const float* __restrict__ RG, const int* __restrict__ bidx,
                        float* __restrict__ out2)
{
    size_t idx = (size_t)blockIdx.x * 256 + threadIdx.x;   // over NATOMS*16
    int n = (int)(idx >> 4), c4 = (int)(idx & 15);
    ((float4*)out2)[idx] = ((const float4*)RG)[(size_t)bidx[n] * 16 + c4];
}

extern "C" void kernel_launch(void* const* d_in, const int* in_sizes, int n_in,
                              void* d_out, int out_size, void* d_ws, size_t ws_size,
                              hipStream_t stream)
{
    const float* x    = (const float*)d_in[0];
    const int*   ei   = (const int*)d_in[1];
    const float* ea   = (const float*)d_in[2];
    const int*   bidx = (const int*)d_in[3];
    const float* Win  = (const float*)d_in[5];
    const float* bin  = (const float*)d_in[6];
    const float* bn0g = (const float*)d_in[7];
    const float* bn0b = (const float*)d_in[8];
    const float* bn0m = (const float*)d_in[9];
    const float* bn0v = (const float*)d_in[10];
    const float* Wc   = (const float*)d_in[11];
    const float* bc   = (const float*)d_in[12];
    const float* bncg = (const float*)d_in[13];
    const float* bncb = (const float*)d_in[14];
    const float* bncm = (const float*)d_in[15];
    const float* bncv = (const float*)d_in[16];
    const float* Ws   = (const float*)d_in[17];
    const float* bs   = (const float*)d_in[18];
    const float* bnsg = (const float*)d_in[19];
    const float* bnsb = (const float*)d_in[20];
    const float* bnsm = (const float*)d_in[21];
    const float* bnsv = (const float*)d_in[22];
    const float* Wp   = (const float*)d_in[23];
    const float* bp   = (const float*)d_in[24];
    const float* Wd1  = (const float*)d_in[25];
    const float* bd1  = (const float*)d_in[26];
    const float* bndg = (const float*)d_in[27];
    const float* bndb = (const float*)d_in[28];
    const float* bndm = (const float*)d_in[29];
    const float* bndv = (const float*)d_in[30];
    const float* Wd2  = (const float*)d_in[31];
    const float* bd2  = (const float*)d_in[32];

    float* out  = (float*)d_out;
    float* out0 = out;
    float* out1 = out + (size_t)NG * LSEQ * HDIM;
    float* out2 = out1 + (size_t)NG * HDIM;

    char* w = (char*)d_ws;
    size_t off = 0;
    auto alloc = [&](size_t bytes) { void* p = w + off; off += (bytes + 255) & ~255ULL; return p; };
    ushort* P      = (ushort*)alloc((size_t)NATOMS * HDIM * 2);   // 46.1 MB
    float*  AGG    = (float*) alloc((size_t)NATOMS * HDIM * 4);   // 92.2 MB
    ushort* TOTAL  = (ushort*)alloc((size_t)NATOMS * HDIM * 2);   // 46.1 MB
    ushort* HB     = (ushort*)alloc((size_t)NPAD * HDIM * 2);     // 46.2 MB
    ushort* WT     = (ushort*)alloc((size_t)HDIM * 2304 * 2);     // 3.5 MB
    ushort* COMB   = (ushort*)alloc((size_t)GPAD * 2304 * 2);     // 3.0 MB
    float*  HS     = (float*) alloc((size_t)NG * HDIM * 4);
    ushort* HSB    = (ushort*)alloc((size_t)GPAD * HDIM * 2);
    ushort* POOLB  = (ushort*)alloc((size_t)GPAD * HDIM * 2);
    ushort* DGB    = (ushort*)alloc((size_t)GPAD * HDIM * 2);
    float*  RECONG = (float*) alloc((size_t)NG * 64 * 4);
    // peak ~242 MB

    const int* src_a = ei;
    const int* dst_a = ei + NEDGE;

    // input MLP (covers HB pad-row zeroing)
    mlp_in_k<<<NPAD / 8, 256, 0, stream>>>(x, Win, bin, bn0g, bn0b, bn0m, bn0v, TOTAL, HB);

    // 3 conv layers
    for (int i = 0; i < 3; i++) {
        const float* Wci  = Wc + (size_t)i * 774 * HDIM;
        const float* Wcei = Wci + (size_t)HDIM * HDIM;     // rows 768..773
        const float* bci  = bc + i * HDIM;
        transpose_cast_k<<<(HDIM * HDIM + 255) / 256, 256, 0, stream>>>(Wci, WT, HDIM, HDIM, HDIM);
        gemm_bt<0><<<dim3(NPAD / 128, HDIM / 128), 256, 0, stream>>>(
            HB, WT, nullptr, P, nullptr, nullptr, nullptr, nullptr, nullptr,
            NATOMS, HDIM, HDIM);
        selfloop_k<<<(NATOMS * H4) / 256, 256, 0, stream>>>(P, bci, AGG);
        edge_k<<<NEDGE, 192, 0, stream>>>(P, src_a, dst_a, ea, Wcei, bci, AGG);
        bn_total_k<<<(NATOMS * H4) / 256, 256, 0, stream>>>(
            AGG, bncg + i * HDIM, bncb + i * HDIM, bncm + i * HDIM, bncv + i * HDIM, TOTAL, HB);
    }

    // pooling -> comb (bf16)
    pool_k<<<GPAD, 192, 0, stream>>>(TOTAL, bidx, COMB);

    // hs = BN(relu(comb @ Ws + bs))
    transpose_cast_k<<<(HDIM * 2304 + 255) / 256, 256, 0, stream>>>(Ws, WT, 2304, HDIM, HDIM);
    gemm_bt<1><<<dim3(GPAD / 128, HDIM / 128), 256, 0, stream>>>(
        COMB, WT, HS, HSB, bs, bnsg, bnsb, bnsm, bnsv, NG, HDIM, 2304);

    // last_hidden broadcast
    bcast_k<<<(NG * LSEQ * H4) / 256, 256, 0, stream>>>(HS, out0);

    // pooler = tanh(hs @ Wp + bp)  -> out1
    transpose_cast_k<<<(HDIM * HDIM + 255) / 256, 256, 0, stream>>>(Wp, WT, HDIM, HDIM, HDIM);
    gemm_bt<2><<<dim3(GPAD / 128, HDIM / 128), 256, 0, stream>>>(
        HSB, WT, out1, POOLB, bp, nullptr, nullptr, nullptr, nullptr, NG, HDIM, HDIM);

    // graph-level decoder: dg = BN(relu(pooler @ Wd1 + bd1))
    transpose_cast_k<<<(HDIM * HDIM + 255) / 256, 256, 0, stream>>>(Wd1, WT, HDIM, HDIM, HDIM);
    gemm_bt<1><<<dim3(GPAD / 128, HDIM / 128), 256, 0, stream>>>(
        POOLB, WT, nullptr, DGB, bd1, bndg, bndb, bndm, bndv, NG, HDIM, HDIM);

    // recon_g = dg @ Wd2 + bd2  (N=64, padded to 128)
    transpose_cast_k<<<(128 * HDIM + 255) / 256, 256, 0, stream>>>(Wd2, WT, HDIM, 64, 128);
    gemm_bt<3><<<dim3(GPAD / 128, 1), 256, 0, stream>>>(
        DGB, WT, RECONG, nullptr, bd2, nullptr, nullptr, nullptr, nullptr, NG, 64, HDIM);

    // expand recon to nodes
    recon_k<<<(NATOMS * 16) / 256, 256, 0, stream>>>(RECONG, bidx, out2);
}

// Round 3
// 914.499 us; speedup vs baseline: 2.9201x; 2.9201x over previous
//
#include <hip/hip_runtime.h>

#define NATOMS 30000
#define NPAD   30080        // 235*128
#define NEDGE  60000
#define HDIM   768
#define H4     192
#define NG     600
#define GPAD   640          // 5*128
#define LSEQ   20
#define BNEPS  1e-5f

typedef __attribute__((ext_vector_type(8))) short bf16x8;
typedef __attribute__((ext_vector_type(4))) float f32x4;

__device__ __forceinline__ ushort f2bf(float f) {
    union { float f; unsigned u; } v; v.f = f;
    unsigned r = v.u + 0x7FFFu + ((v.u >> 16) & 1u);
    return (ushort)(r >> 16);
}
__device__ __forceinline__ float bf2f(ushort u) {
    union { unsigned u; float f; } v; v.u = ((unsigned)u) << 16; return v.f;
}
__device__ __forceinline__ ushort4 pack4(float4 v) {
    ushort4 r; r.x = f2bf(v.x); r.y = f2bf(v.y); r.z = f2bf(v.z); r.w = f2bf(v.w); return r;
}
__device__ __forceinline__ float4 unpack4(ushort4 u) {
    float4 r; r.x = bf2f(u.x); r.y = bf2f(u.y); r.z = bf2f(u.z); r.w = bf2f(u.w); return r;
}

// ---------- input MLP: h0 = BN(relu(x@Win+bin)); TOTAL=bf16(h0); HB=bf16(h0); zero HB pad rows ----------
__global__ __launch_bounds__(256) void mlp_in_k(
    const float* __restrict__ x, const float* __restrict__ Win, const float* __restrict__ bin,
    const float* __restrict__ g, const float* __restrict__ b,
    const float* __restrict__ m, const float* __restrict__ vv,
    ushort* __restrict__ TOTAL, ushort* __restrict__ HB)
{
    __shared__ float xs[8][64];
    int r0 = blockIdx.x * 8;
    for (int i = threadIdx.x; i < 8 * 64; i += 256) {
        int rr = i >> 6, kk = i & 63;
        int row = r0 + rr;
        xs[rr][kk] = (row < NATOMS) ? x[(size_t)row * 64 + kk] : 0.f;
    }
    __syncthreads();
    for (int c = threadIdx.x; c < HDIM; c += 256) {
        float s = g[c] * rsqrtf(vv[c] + BNEPS);
        float mm = m[c], bb = b[c];
        float acc[8];
        #pragma unroll
        for (int rr = 0; rr < 8; rr++) acc[rr] = bin[c];
        for (int k = 0; k < 64; k++) {
            float w = Win[k * HDIM + c];
            #pragma unroll
            for (int rr = 0; rr < 8; rr++) acc[rr] += xs[rr][k] * w;
        }
        #pragma unroll
        for (int rr = 0; rr < 8; rr++) {
            int row = r0 + rr;
            if (row < NATOMS) {
                float hv = (fmaxf(acc[rr], 0.f) - mm) * s + bb;
                ushort hb = f2bf(hv);
                TOTAL[(size_t)row * HDIM + c] = hb;
                HB[(size_t)row * HDIM + c] = hb;
            } else if (row < NPAD) {
                HB[(size_t)row * HDIM + c] = 0;
            }
        }
    }
}

// ---------- transpose + cast: W[K][Nsrc] f32 -> WT[Npad][K] bf16 (pad rows zero) ----------
__global__ void transpose_cast_k(const float* __restrict__ W, ushort* __restrict__ WT,
                                 int K, int Nsrc, int Npad)
{
    int idx = blockIdx.x * 256 + threadIdx.x;   // over Npad*K
    if (idx >= Npad * K) return;
    int n = idx / K, k = idx - n * K;
    float v = (n < Nsrc) ? W[(size_t)k * Nsrc + n] : 0.f;
    WT[idx] = f2bf(v);
}

// ---------- bf16 MFMA GEMM: C = A[Mpad][K] @ Bt[Npad][K]^T, fused epilogues ----------
// EPI: 0 = none, 1 = bias+relu+BN, 2 = bias+tanh, 3 = bias
template <int EPI>
__global__ __launch_bounds__(256) void gemm_bt(
    const ushort* __restrict__ A, const ushort* __restrict__ Bt,
    float* __restrict__ Cf, ushort* __restrict__ Cb,
    const float* __restrict__ bias,
    const float* __restrict__ bng, const float* __restrict__ bnb,
    const float* __restrict__ bnm, const float* __restrict__ bnv,
    int Mreal, int Nreal, int K)
{
    __shared__ ushort Ash[128 * 40];
    __shared__ ushort Bsh[128 * 40];
    int t = threadIdx.x;
    int lane = t & 63, wave = t >> 6;
    int wr = wave >> 1, wc = wave & 1;
    int brow = blockIdx.x, bcol = blockIdx.y;

    f32x4 acc[4][4];
    #pragma unroll
    for (int i = 0; i < 4; i++)
        #pragma unroll
        for (int j = 0; j < 4; j++) acc[i][j] = (f32x4)0.f;

    const int r = t >> 1, half = t & 1;
    const ushort* Ag = A + (size_t)(brow * 128 + r) * K + half * 16;
    const ushort* Bg = Bt + (size_t)(bcol * 128 + r) * K + half * 16;
    const int lr = lane & 15, lk = (lane >> 4) * 8;

    for (int kt = 0; kt < K; kt += 32) {
        uint4 a0 = *(const uint4*)(Ag + kt);
        uint4 a1 = *(const uint4*)(Ag + kt + 8);
        uint4 b0 = *(const uint4*)(Bg + kt);
        uint4 b1 = *(const uint4*)(Bg + kt + 8);
        *(uint4*)(&Ash[r * 40 + half * 16]) = a0;
        *(uint4*)(&Ash[r * 40 + half * 16 + 8]) = a1;
        *(uint4*)(&Bsh[r * 40 + half * 16]) = b0;
        *(uint4*)(&Bsh[r * 40 + half * 16 + 8]) = b1;
        __syncthreads();

        bf16x8 af[4], bfr[4];
        #pragma unroll
        for (int mf = 0; mf < 4; mf++)
            af[mf] = *(const bf16x8*)(&Ash[(wr * 64 + mf * 16 + lr) * 40 + lk]);
        #pragma unroll
        for (int nf = 0; nf < 4; nf++)
            bfr[nf] = *(const bf16x8*)(&Bsh[(wc * 64 + nf * 16 + lr) * 40 + lk]);
        #pragma unroll
        for (int mf = 0; mf < 4; mf++)
            #pragma unroll
            for (int nf = 0; nf < 4; nf++)
                acc[mf][nf] = __builtin_amdgcn_mfma_f32_16x16x32_bf16(af[mf], bfr[nf], acc[mf][nf], 0, 0, 0);
        __syncthreads();
    }

    const int lq = lane >> 4;
    #pragma unroll
    for (int mf = 0; mf < 4; mf++) {
        #pragma unroll
        for (int nf = 0; nf < 4; nf++) {
            int col = bcol * 128 + wc * 64 + nf * 16 + lr;
            #pragma unroll
            for (int rg = 0; rg < 4; rg++) {
                int row = brow * 128 + wr * 64 + mf * 16 + lq * 4 + rg;
                if (row < Mreal && col < Nreal) {
                    float v = acc[mf][nf][rg];
                    if (EPI >= 1) v += bias[col];
                    if (EPI == 1) {
                        v = fmaxf(v, 0.f);
                        float s = bng[col] * rsqrtf(bnv[col] + BNEPS);
                        v = (v - bnm[col]) * s + bnb[col];
                    } else if (EPI == 2) {
                        v = tanhf(v);
                    }
                    size_t o = (size_t)row * Nreal + col;
                    if (Cf) Cf[o] = v;
                    if (Cb) Cb[o] = f2bf(v);
                }
            }
        }
    }
}

// ================= CSR build (once per launch; shared by all 3 conv layers) =================

__global__ void zero_k(int* __restrict__ p, int n)
{
    int i = blockIdx.x * 256 + threadIdx.x;
    if (i < n) p[i] = 0;
}

__global__ void count_k(const int* __restrict__ dst_a, int* __restrict__ cnt)
{
    int e = blockIdx.x * 256 + threadIdx.x;
    if (e < NEDGE) atomicAdd(&cnt[dst_a[e]], 1);
}

// single-block exclusive scan of cnt[0..NATOMS) -> row_off[0..NATOMS], cur copy
__global__ __launch_bounds__(1024) void scan_k(const int* __restrict__ cnt,
                                               int* __restrict__ row_off,
                                               int* __restrict__ cur)
{
    __shared__ int part[1024];
    const int CH = (NATOMS + 1023) / 1024;     // 30
    int t = threadIdx.x;
    int base = t * CH;
    int s = 0;
    for (int i = base; i < base + CH && i < NATOMS; i++) s += cnt[i];
    part[t] = s;
    __syncthreads();
    for (int off = 1; off < 1024; off <<= 1) {
        int v = (t >= off) ? part[t - off] : 0;
        __syncthreads();
        part[t] += v;
        __syncthreads();
    }
    int excl = part[t] - s;
    for (int i = base; i < base + CH && i < NATOMS; i++) {
        row_off[i] = excl;
        cur[i] = excl;
        excl += cnt[i];
    }
    if (t == 1023) row_off[NATOMS] = part[1023];
}

// scatter edges into CSR order; pre-gather edge_attr (8 floats/slot, [0..5] used)
__global__ void fill_k(const int* __restrict__ src_a, const int* __restrict__ dst_a,
                       const float* __restrict__ ea,
                       int* __restrict__ cur, int* __restrict__ srcs, float* __restrict__ eas)
{
    int e = blockIdx.x * 256 + threadIdx.x;
    if (e >= NEDGE) return;
    int d = dst_a[e];
    int pos = atomicAdd(&cur[d], 1);
    srcs[pos] = src_a[e];
    float* o = eas + (size_t)pos * 8;
    o[0] = ea[e * 6 + 0]; o[1] = ea[e * 6 + 1]; o[2] = ea[e * 6 + 2];
    o[3] = ea[e * 6 + 3]; o[4] = ea[e * 6 + 4]; o[5] = ea[e * 6 + 5];
}

// ---------- fused per-node aggregation: self-loop + edge messages + BN + TOTAL + HB ----------
// block = one node, 192 threads = 768 channels (float4 each)
__global__ __launch_bounds__(192) void node_agg_k(
    const ushort* __restrict__ P, const int* __restrict__ row_off,
    const int* __restrict__ srcs, const float* __restrict__ eas,
    const float* __restrict__ Wce, const float* __restrict__ bc,
    const float* __restrict__ g, const float* __restrict__ b,
    const float* __restrict__ m, const float* __restrict__ vv,
    ushort* __restrict__ TOTAL, ushort* __restrict__ HB)
{
    int n = blockIdx.x;
    int c4 = threadIdx.x;
    const float4* W4 = (const float4*)Wce;
    float4 w0 = W4[0 * H4 + c4], w1 = W4[1 * H4 + c4], w2 = W4[2 * H4 + c4];
    float4 w3 = W4[3 * H4 + c4], w4 = W4[4 * H4 + c4], w5 = W4[5 * H4 + c4];
    float4 bb = ((const float4*)bc)[c4];

    // self-loop message (edge_attr = 0)
    float4 p = unpack4(((const ushort4*)P)[(size_t)n * H4 + c4]);
    float4 acc;
    acc.x = fmaxf(p.x + bb.x, 0.f); acc.y = fmaxf(p.y + bb.y, 0.f);
    acc.z = fmaxf(p.z + bb.z, 0.f); acc.w = fmaxf(p.w + bb.w, 0.f);

    int lo = row_off[n], hi = row_off[n + 1];
    for (int j = lo; j < hi; j++) {
        int s = srcs[j];
        const float* e8 = eas + (size_t)j * 8;
        float4 eA = *(const float4*)(e8);       // e0..e3
        float e4v = e8[4], e5v = e8[5];
        float4 ps = unpack4(((const ushort4*)P)[(size_t)s * H4 + c4]);
        float4 v;
        v.x = fmaxf(ps.x + eA.x * w0.x + eA.y * w1.x + eA.z * w2.x + eA.w * w3.x + e4v * w4.x + e5v * w5.x + bb.x, 0.f);
        v.y = fmaxf(ps.y + eA.x * w0.y + eA.y * w1.y + eA.z * w2.y + eA.w * w3.y + e4v * w4.y + e5v * w5.y + bb.y, 0.f);
        v.z = fmaxf(ps.z + eA.x * w0.z + eA.y * w1.z + eA.z * w2.z + eA.w * w3.z + e4v * w4.z + e5v * w5.z + bb.z, 0.f);
        v.w = fmaxf(ps.w + eA.x * w0.w + eA.y * w1.w + eA.z * w2.w + eA.w * w3.w + e4v * w4.w + e5v * w5.w + bb.w, 0.f);
        acc.x += v.x; acc.y += v.y; acc.z += v.z; acc.w += v.w;
    }

    // BN + TOTAL += + HB
    float4 gg = ((const float4*)g)[c4], bo = ((const float4*)b)[c4];
    float4 mm = ((const float4*)m)[c4], vq = ((const float4*)vv)[c4];
    float4 hv;
    hv.x = (acc.x - mm.x) * (gg.x * rsqrtf(vq.x + BNEPS)) + bo.x;
    hv.y = (acc.y - mm.y) * (gg.y * rsqrtf(vq.y + BNEPS)) + bo.y;
    hv.z = (acc.z - mm.z) * (gg.z * rsqrtf(vq.z + BNEPS)) + bo.z;
    hv.w = (acc.w - mm.w) * (gg.w * rsqrtf(vq.w + BNEPS)) + bo.w;
    size_t idx = (size_t)n * H4 + c4;
    float4 tt = unpack4(((const ushort4*)TOTAL)[idx]);
    tt.x += hv.x; tt.y += hv.y; tt.z += hv.z; tt.w += hv.w;
    ((ushort4*)TOTAL)[idx] = pack4(tt);
    ((ushort4*)HB)[idx] = pack4(hv);
}

// ---------- per-graph pooling -> COMB bf16 [GPAD][2304] = [mean | add | max] ----------
__global__ __launch_bounds__(192) void pool_k(const ushort* __restrict__ TOTAL,
                                              const int* __restrict__ bidx,
                                              ushort* __restrict__ COMB)
{
    int g = blockIdx.x;
    int c4 = threadIdx.x;
    ushort4* C4 = (ushort4*)COMB;
    if (g >= NG) {
        ushort4 z; z.x = z.y = z.z = z.w = 0;
        C4[(size_t)g * 576 + c4] = z;
        C4[(size_t)g * 576 + 192 + c4] = z;
        C4[(size_t)g * 576 + 384 + c4] = z;
        return;
    }
    int lo, hi;
    { int a = 0, b = NATOMS; while (a < b) { int mid = (a + b) >> 1; if (bidx[mid] < g) a = mid + 1; else b = mid; } lo = a; }
    { int a = lo, b = NATOMS; while (a < b) { int mid = (a + b) >> 1; if (bidx[mid] <= g) a = mid + 1; else b = mid; } hi = a; }
    int cnt = hi - lo;
    float4 sum = {0.f, 0.f, 0.f, 0.f};
    float4 mx = {-INFINITY, -INFINITY, -INFINITY, -INFINITY};
    for (int r = lo; r < hi; r++) {
        float4 v = unpack4(((const ushort4*)TOTAL)[(size_t)r * H4 + c4]);
        sum.x += v.x; sum.y += v.y; sum.z += v.z; sum.w += v.w;
        mx.x = fmaxf(mx.x, v.x); mx.y = fmaxf(mx.y, v.y);
        mx.z = fmaxf(mx.z, v.z); mx.w = fmaxf(mx.w, v.w);
    }
    float inv = 1.f / fmaxf((float)cnt, 1.f);
    if (cnt == 0) { mx.x = mx.y = mx.z = mx.w = 0.f; }
    float4 mean = {sum.x * inv, sum.y * inv, sum.z * inv, sum.w * inv};
    C4[(size_t)g * 576 + c4] = pack4(mean);
    C4[(size_t)g * 576 + 192 + c4] = pack4(sum);
    C4[(size_t)g * 576 + 384 + c4] = pack4(mx);
}

// ---------- last_hidden broadcast: out0[g][l][c] = HS[g][c] ----------
__global__ void bcast_k(const float* __restrict__ HS, float* __restrict__ out0)
{
    size_t idx = (size_t)blockIdx.x * 256 + threadIdx.x;   // over NG*LSEQ*H4
    int c4 = (int)(idx % H4);
    int g = (int)(idx / ((size_t)H4 * LSEQ));
    ((float4*)out0)[idx] = ((const float4*)HS)[(size_t)g * H4 + c4];
}

// ---------- recon gather: out2[n] = RECONG[bidx[n]] ----------
__global__ void recon_k(const float* __restrict__ RG, const int* __restrict__ bidx,
                        float* __restrict__ out2)
{
    size_t idx = (size_t)blockIdx.x * 256 + threadIdx.x;   // over NATOMS*16
    int n = (int)(idx >> 4), c4 = (int)(idx & 15);
    ((float4*)out2)[idx] = ((const float4*)RG)[(size_t)bidx[n] * 16 + c4];
}

extern "C" void kernel_launch(void* const* d_in, const int* in_sizes, int n_in,
                              void* d_out, int out_size, void* d_ws, size_t ws_size,
                              hipStream_t stream)
{
    const float* x    = (const float*)d_in[0];
    const int*   ei   = (const int*)d_in[1];
    const float* ea   = (const float*)d_in[2];
    const int*   bidx = (const int*)d_in[3];
    const float* Win  = (const float*)d_in[5];
    const float* bin  = (const float*)d_in[6];
    const float* bn0g = (const float*)d_in[7];
    const float* bn0b = (const float*)d_in[8];
    const float* bn0m = (const float*)d_in[9];
    const float* bn0v = (const float*)d_in[10];
    const float* Wc   = (const float*)d_in[11];
    const float* bc   = (const float*)d_in[12];
    const float* bncg = (const float*)d_in[13];
    const float* bncb = (const float*)d_in[14];
    const float* bncm = (const float*)d_in[15];
    const float* bncv = (const float*)d_in[16];
    const float* Ws   = (const float*)d_in[17];
    const float* bs   = (const float*)d_in[18];
    const float* bnsg = (const float*)d_in[19];
    const float* bnsb = (const float*)d_in[20];
    const float* bnsm = (const float*)d_in[21];
    const float* bnsv = (const float*)d_in[22];
    const float* Wp   = (const float*)d_in[23];
    const float* bp   = (const float*)d_in[24];
    const float* Wd1  = (const float*)d_in[25];
    const float* bd1  = (const float*)d_in[26];
    const float* bndg = (const float*)d_in[27];
    const float* bndb = (const float*)d_in[28];
    const float* bndm = (const float*)d_in[29];
    const float* bndv = (const float*)d_in[30];
    const float* Wd2  = (const float*)d_in[31];
    const float* bd2  = (const float*)d_in[32];

    float* out  = (float*)d_out;
    float* out0 = out;
    float* out1 = out + (size_t)NG * LSEQ * HDIM;
    float* out2 = out1 + (size_t)NG * HDIM;

    char* w = (char*)d_ws;
    size_t off = 0;
    auto alloc = [&](size_t bytes) { void* p = w + off; off += (bytes + 255) & ~255ULL; return p; };
    ushort* P      = (ushort*)alloc((size_t)NATOMS * HDIM * 2);   // 46.1 MB
    ushort* TOTAL  = (ushort*)alloc((size_t)NATOMS * HDIM * 2);   // 46.1 MB
    ushort* HB     = (ushort*)alloc((size_t)NPAD * HDIM * 2);     // 46.2 MB
    ushort* WT     = (ushort*)alloc((size_t)HDIM * 2304 * 2);     // 3.5 MB
    ushort* COMB   = (ushort*)alloc((size_t)GPAD * 2304 * 2);     // 3.0 MB
    float*  HS     = (float*) alloc((size_t)NG * HDIM * 4);
    ushort* HSB    = (ushort*)alloc((size_t)GPAD * HDIM * 2);
    ushort* POOLB  = (ushort*)alloc((size_t)GPAD * HDIM * 2);
    ushort* DGB    = (ushort*)alloc((size_t)GPAD * HDIM * 2);
    float*  RECONG = (float*) alloc((size_t)NG * 64 * 4);
    int*    cnt    = (int*)   alloc((size_t)NATOMS * 4);
    int*    row_off= (int*)   alloc((size_t)(NATOMS + 1) * 4);
    int*    cur    = (int*)   alloc((size_t)NATOMS * 4);
    int*    srcs   = (int*)   alloc((size_t)NEDGE * 4);
    float*  eas    = (float*) alloc((size_t)NEDGE * 8 * 4);       // 1.9 MB
    // peak ~150 MB

    const int* src_a = ei;
    const int* dst_a = ei + NEDGE;

    // input MLP (covers HB pad-row zeroing)
    mlp_in_k<<<NPAD / 8, 256, 0, stream>>>(x, Win, bin, bn0g, bn0b, bn0m, bn0v, TOTAL, HB);

    // CSR build (once; same edge list for all layers)
    zero_k<<<(NATOMS + 255) / 256, 256, 0, stream>>>(cnt, NATOMS);
    count_k<<<(NEDGE + 255) / 256, 256, 0, stream>>>(dst_a, cnt);
    scan_k<<<1, 1024, 0, stream>>>(cnt, row_off, cur);
    fill_k<<<(NEDGE + 255) / 256, 256, 0, stream>>>(src_a, dst_a, ea, cur, srcs, eas);

    // 3 conv layers
    for (int i = 0; i < 3; i++) {
        const float* Wci  = Wc + (size_t)i * 774 * HDIM;
        const float* Wcei = Wci + (size_t)HDIM * HDIM;     // rows 768..773
        const float* bci  = bc + i * HDIM;
        transpose_cast_k<<<(HDIM * HDIM + 255) / 256, 256, 0, stream>>>(Wci, WT, HDIM, HDIM, HDIM);
        gemm_bt<0><<<dim3(NPAD / 128, HDIM / 128), 256, 0, stream>>>(
            HB, WT, nullptr, P, nullptr, nullptr, nullptr, nullptr, nullptr,
            NATOMS, HDIM, HDIM);
        node_agg_k<<<NATOMS, 192, 0, stream>>>(
            P, row_off, srcs, eas, Wcei, bci,
            bncg + i * HDIM, bncb + i * HDIM, bncm + i * HDIM, bncv + i * HDIM, TOTAL, HB);
    }

    // pooling -> comb (bf16)
    pool_k<<<GPAD, 192, 0, stream>>>(TOTAL, bidx, COMB);

    // hs = BN(relu(comb @ Ws + bs))
    transpose_cast_k<<<(HDIM * 2304 + 255) / 256, 256, 0, stream>>>(Ws, WT, 2304, HDIM, HDIM);
    gemm_bt<1><<<dim3(GPAD / 128, HDIM / 128), 256, 0, stream>>>(
        COMB, WT, HS, HSB, bs, bnsg, bnsb, bnsm, bnsv, NG, HDIM, 2304);

    // last_hidden broadcast
    bcast_k<<<(NG * LSEQ * H4) / 256, 256, 0, stream>>>(HS, out0);

    // pooler = tanh(hs @ Wp + bp)  -> out1
    transpose_cast_k<<<(HDIM * HDIM + 255) / 256, 256, 0, stream>>>(Wp, WT, HDIM, HDIM, HDIM);
    gemm_bt<2><<<dim3(GPAD / 128, HDIM / 128), 256, 0, stream>>>(
        HSB, WT, out1, POOLB, bp, nullptr, nullptr, nullptr, nullptr, NG, HDIM, HDIM);

    // graph-level decoder: dg = BN(relu(pooler @ Wd1 + bd1))
    transpose_cast_k<<<(HDIM * HDIM + 255) / 256, 256, 0, stream>>>(Wd1, WT, HDIM, HDIM, HDIM);
    gemm_bt<1><<<dim3(GPAD / 128, HDIM / 128), 256, 0, stream>>>(
        POOLB, WT, nullptr, DGB, bd1, bndg, bndb, bndm, bndv, NG, HDIM, HDIM);

    // recon_g = dg @ Wd2 + bd2  (N=64, padded to 128)
    transpose_cast_k<<<(128 * HDIM + 255) / 256, 256, 0, stream>>>(Wd2, WT, HDIM, 64, 128);
    gemm_bt<3><<<dim3(GPAD / 128, 1), 256, 0, stream>>>(
        DGB, WT, RECONG, nullptr, bd2, nullptr, nullptr, nullptr, nullptr, NG, 64, HDIM);

    // expand recon to nodes
    recon_k<<<(NATOMS * 16) / 256, 256, 0, stream>>>(RECONG, bidx, out2);
}

// Round 4
// 855.111 us; speedup vs baseline: 3.1230x; 1.0695x over previous
//
#include <hip/hip_runtime.h>

#define NATOMS 30000
#define NPAD   30080        // 235*128
#define NEDGE  60000
#define HDIM   768
#define H4     192
#define NG     600
#define GPAD   640          // 5*128
#define LSEQ   20
#define BNEPS  1e-5f

typedef __attribute__((ext_vector_type(8))) short bf16x8;
typedef __attribute__((ext_vector_type(4))) float f32x4;

__device__ __forceinline__ ushort f2bf(float f) {
    union { float f; unsigned u; } v; v.f = f;
    unsigned r = v.u + 0x7FFFu + ((v.u >> 16) & 1u);
    return (ushort)(r >> 16);
}
__device__ __forceinline__ float bf2f(ushort u) {
    union { unsigned u; float f; } v; v.u = ((unsigned)u) << 16; return v.f;
}
__device__ __forceinline__ ushort4 pack4(float4 v) {
    ushort4 r; r.x = f2bf(v.x); r.y = f2bf(v.y); r.z = f2bf(v.z); r.w = f2bf(v.w); return r;
}
__device__ __forceinline__ float4 unpack4(ushort4 u) {
    float4 r; r.x = bf2f(u.x); r.y = bf2f(u.y); r.z = bf2f(u.z); r.w = bf2f(u.w); return r;
}
// async global->LDS, 16B per lane; LDS dest must be wave-uniform, global src per-lane
__device__ __forceinline__ void gl_lds16(const ushort* g, ushort* l) {
    __builtin_amdgcn_global_load_lds(
        (const __attribute__((address_space(1))) void*)(g),
        (__attribute__((address_space(3))) void*)(l), 16, 0, 0);
}

// ---------- cast x f32 -> bf16 ----------
__global__ void cast_x_k(const float* __restrict__ x, ushort* __restrict__ XB)
{
    size_t idx = (size_t)blockIdx.x * 256 + threadIdx.x;   // over NATOMS*64/4
    float4 v = ((const float4*)x)[idx];
    ((ushort4*)XB)[idx] = pack4(v);
}

// ---------- transpose + cast: W[K][Nsrc] f32 -> WT[Npad][K] bf16 (pad rows zero) ----------
__global__ void transpose_cast_k(const float* __restrict__ W, ushort* __restrict__ WT,
                                 int K, int Nsrc, int Npad)
{
    int idx = blockIdx.x * 256 + threadIdx.x;   // over Npad*K
    if (idx >= Npad * K) return;
    int n = idx / K, k = idx - n * K;
    float v = (n < Nsrc) ? W[(size_t)k * Nsrc + n] : 0.f;
    WT[idx] = f2bf(v);
}

// ---------- bf16 MFMA GEMM (m97-style global_load_lds staging, linear LDS [128][32]) ----------
// C = A[.][K] @ Bt[.][K]^T ; EPI: 0 = none, 1 = bias+relu+BN, 2 = bias+tanh, 3 = bias
template <int EPI>
__global__ __launch_bounds__(256) void gemm_bt(
    const ushort* __restrict__ A, const ushort* __restrict__ Bt,
    float* __restrict__ Cf, ushort* __restrict__ Cb, ushort* __restrict__ Cb2,
    const float* __restrict__ bias,
    const float* __restrict__ bng, const float* __restrict__ bnb,
    const float* __restrict__ bnm, const float* __restrict__ bnv,
    int Mreal, int Nreal, int K)
{
    __shared__ ushort As[128 * 32];
    __shared__ ushort Bs[128 * 32];
    int t = threadIdx.x;
    int lane = t & 63, wave = t >> 6;
    int wr = wave >> 1, wc = wave & 1;
    int brow = blockIdx.x, bcol = blockIdx.y;

    f32x4 acc[4][4];
    #pragma unroll
    for (int i = 0; i < 4; i++)
        #pragma unroll
        for (int j = 0; j < 4; j++) acc[i][j] = (f32x4)0.f;

    // staging: wave handles LDS chunks {2w, 2w+1} of A and B (1 KB each).
    // chunk c, lane l covers LDS byte lambda = c*1024 + l*16 -> row = c*16 + (l>>2), col elem = (l&3)*8
    const int r0 = wave * 32 + (lane >> 2);        // row of chunk 2w
    const int ce = (lane & 3) * 8;
    const ushort* Ag0 = A + (size_t)(brow * 128 + r0) * K + ce;
    const ushort* Ag1 = A + (size_t)(brow * 128 + r0 + 16) * K + ce;
    const ushort* Bg0 = Bt + (size_t)(bcol * 128 + r0) * K + ce;
    const ushort* Bg1 = Bt + (size_t)(bcol * 128 + r0 + 16) * K + ce;
    ushort* Al0 = As + wave * 1024;                // in ushorts: 2 chunks = 1024 elems
    ushort* Al1 = As + wave * 1024 + 512;
    ushort* Bl0 = Bs + wave * 1024;
    ushort* Bl1 = Bs + wave * 1024 + 512;

    const int lr = lane & 15, lk = (lane >> 4) * 8;

    for (int kt = 0; kt < K; kt += 32) {
        __syncthreads();                            // previous reads done
        gl_lds16(Ag0 + kt, Al0);
        gl_lds16(Ag1 + kt, Al1);
        gl_lds16(Bg0 + kt, Bl0);
        gl_lds16(Bg1 + kt, Bl1);
        __syncthreads();                            // loads visible (compiler drains vmcnt)

        bf16x8 af[4], bfr[4];
        #pragma unroll
        for (int mf = 0; mf < 4; mf++)
            af[mf] = *(const bf16x8*)(&As[(wr * 64 + mf * 16 + lr) * 32 + lk]);
        #pragma unroll
        for (int nf = 0; nf < 4; nf++)
            bfr[nf] = *(const bf16x8*)(&Bs[(wc * 64 + nf * 16 + lr) * 32 + lk]);
        #pragma unroll
        for (int mf = 0; mf < 4; mf++)
            #pragma unroll
            for (int nf = 0; nf < 4; nf++)
                acc[mf][nf] = __builtin_amdgcn_mfma_f32_16x16x32_bf16(af[mf], bfr[nf], acc[mf][nf], 0, 0, 0);
    }

    const int lq = lane >> 4;
    #pragma unroll
    for (int mf = 0; mf < 4; mf++) {
        #pragma unroll
        for (int nf = 0; nf < 4; nf++) {
            int col = bcol * 128 + wc * 64 + nf * 16 + lr;
            #pragma unroll
            for (int rg = 0; rg < 4; rg++) {
                int row = brow * 128 + wr * 64 + mf * 16 + lq * 4 + rg;
                if (row < Mreal && col < Nreal) {
                    float v = acc[mf][nf][rg];
                    if (EPI >= 1) v += bias[col];
                    if (EPI == 1) {
                        v = fmaxf(v, 0.f);
                        float s = bng[col] * rsqrtf(bnv[col] + BNEPS);
                        v = (v - bnm[col]) * s + bnb[col];
                    } else if (EPI == 2) {
                        v = tanhf(v);
                    }
                    size_t o = (size_t)row * Nreal + col;
                    if (Cf) Cf[o] = v;
                    if (Cb) Cb[o] = f2bf(v);
                    if (Cb2) Cb2[o] = f2bf(v);
                }
            }
        }
    }
}

// ================= CSR build (once per launch; shared by all 3 conv layers) =================

__global__ void zero_k(int* __restrict__ p, int n)
{
    int i = blockIdx.x * 256 + threadIdx.x;
    if (i < n) p[i] = 0;
}

__global__ void count_k(const int* __restrict__ dst_a, int* __restrict__ cnt)
{
    int e = blockIdx.x * 256 + threadIdx.x;
    if (e < NEDGE) atomicAdd(&cnt[dst_a[e]], 1);
}

// single-block exclusive scan of cnt[0..NATOMS) -> row_off[0..NATOMS], cur copy
__global__ __launch_bounds__(1024) void scan_k(const int* __restrict__ cnt,
                                               int* __restrict__ row_off,
                                               int* __restrict__ cur)
{
    __shared__ int part[1024];
    const int CH = (NATOMS + 1023) / 1024;     // 30
    int t = threadIdx.x;
    int base = t * CH;
    int s = 0;
    for (int i = base; i < base + CH && i < NATOMS; i++) s += cnt[i];
    part[t] = s;
    __syncthreads();
    for (int off = 1; off < 1024; off <<= 1) {
        int v = (t >= off) ? part[t - off] : 0;
        __syncthreads();
        part[t] += v;
        __syncthreads();
    }
    int excl = part[t] - s;
    for (int i = base; i < base + CH && i < NATOMS; i++) {
        row_off[i] = excl;
        cur[i] = excl;
        excl += cnt[i];
    }
    if (t == 1023) row_off[NATOMS] = part[1023];
}

// scatter edges into CSR order; pre-gather edge_attr (8 floats/slot, [0..5] used)
__global__ void fill_k(const int* __restrict__ src_a, const int* __restrict__ dst_a,
                       const float* __restrict__ ea,
                       int* __restrict__ cur, int* __restrict__ srcs, float* __restrict__ eas)
{
    int e = blockIdx.x * 256 + threadIdx.x;
    if (e >= NEDGE) return;
    int d = dst_a[e];
    int pos = atomicAdd(&cur[d], 1);
    srcs[pos] = src_a[e];
    float* o = eas + (size_t)pos * 8;
    o[0] = ea[e * 6 + 0]; o[1] = ea[e * 6 + 1]; o[2] = ea[e * 6 + 2];
    o[3] = ea[e * 6 + 3]; o[4] = ea[e * 6 + 4]; o[5] = ea[e * 6 + 5];
}

// ---------- fused per-node aggregation (4 nodes/block): self-loop + edges + BN + TOTAL + HB ----------
#define NPN 4
__global__ __launch_bounds__(192) void node_agg_k(
    const ushort* __restrict__ P, const int* __restrict__ row_off,
    const int* __restrict__ srcs, const float* __restrict__ eas,
    const float* __restrict__ Wce, const float* __restrict__ bc,
    const float* __restrict__ g, const float* __restrict__ b,
    const float* __restrict__ m, const float* __restrict__ vv,
    ushort* __restrict__ TOTAL, ushort* __restrict__ HB)
{
    int n0 = blockIdx.x * NPN;
    int c4 = threadIdx.x;
    const float4* W4 = (const float4*)Wce;
    float4 w0 = W4[0 * H4 + c4], w1 = W4[1 * H4 + c4], w2 = W4[2 * H4 + c4];
    float4 w3 = W4[3 * H4 + c4], w4 = W4[4 * H4 + c4], w5 = W4[5 * H4 + c4];
    float4 bb = ((const float4*)bc)[c4];
    float4 gg = ((const float4*)g)[c4], bo = ((const float4*)b)[c4];
    float4 mm = ((const float4*)m)[c4], vq = ((const float4*)vv)[c4];
    float4 sc;
    sc.x = gg.x * rsqrtf(vq.x + BNEPS); sc.y = gg.y * rsqrtf(vq.y + BNEPS);
    sc.z = gg.z * rsqrtf(vq.z + BNEPS); sc.w = gg.w * rsqrtf(vq.w + BNEPS);

    for (int u = 0; u < NPN; u++) {
        int n = n0 + u;
        if (n >= NATOMS) return;
        // self-loop message (edge_attr = 0)
        float4 p = unpack4(((const ushort4*)P)[(size_t)n * H4 + c4]);
        float4 acc;
        acc.x = fmaxf(p.x + bb.x, 0.f); acc.y = fmaxf(p.y + bb.y, 0.f);
        acc.z = fmaxf(p.z + bb.z, 0.f); acc.w = fmaxf(p.w + bb.w, 0.f);

        int lo = row_off[n], hi = row_off[n + 1];
        for (int j = lo; j < hi; j++) {
            int s = srcs[j];
            const float* e8 = eas + (size_t)j * 8;
            float4 eA = *(const float4*)(e8);       // e0..e3
            float e4v = e8[4], e5v = e8[5];
            float4 ps = unpack4(((const ushort4*)P)[(size_t)s * H4 + c4]);
            float4 v;
            v.x = fmaxf(ps.x + eA.x * w0.x + eA.y * w1.x + eA.z * w2.x + eA.w * w3.x + e4v * w4.x + e5v * w5.x + bb.x, 0.f);
            v.y = fmaxf(ps.y + eA.x * w0.y + eA.y * w1.y + eA.z * w2.y + eA.w * w3.y + e4v * w4.y + e5v * w5.y + bb.y, 0.f);
            v.z = fmaxf(ps.z + eA.x * w0.z + eA.y * w1.z + eA.z * w2.z + eA.w * w3.z + e4v * w4.z + e5v * w5.z + bb.z, 0.f);
            v.w = fmaxf(ps.w + eA.x * w0.w + eA.y * w1.w + eA.z * w2.w + eA.w * w3.w + e4v * w4.w + e5v * w5.w + bb.w, 0.f);
            acc.x += v.x; acc.y += v.y; acc.z += v.z; acc.w += v.w;
        }

        float4 hv;
        hv.x = (acc.x - mm.x) * sc.x + bo.x;
        hv.y = (acc.y - mm.y) * sc.y + bo.y;
        hv.z = (acc.z - mm.z) * sc.z + bo.z;
        hv.w = (acc.w - mm.w) * sc.w + bo.w;
        size_t idx = (size_t)n * H4 + c4;
        float4 tt = unpack4(((const ushort4*)TOTAL)[idx]);
        tt.x += hv.x; tt.y += hv.y; tt.z += hv.z; tt.w += hv.w;
        ((ushort4*)TOTAL)[idx] = pack4(tt);
        ((ushort4*)HB)[idx] = pack4(hv);
    }
}

// ---------- per-graph pooling -> COMB bf16 [GPAD][2304] = [mean | add | max] ----------
__global__ __launch_bounds__(192) void pool_k(const ushort* __restrict__ TOTAL,
                                              const int* __restrict__ bidx,
                                              ushort* __restrict__ COMB)
{
    int g = blockIdx.x;
    int c4 = threadIdx.x;
    ushort4* C4 = (ushort4*)COMB;
    if (g >= NG) return;       // pad rows of COMB never affect masked outputs
    int lo, hi;
    { int a = 0, b = NATOMS; while (a < b) { int mid = (a + b) >> 1; if (bidx[mid] < g) a = mid + 1; else b = mid; } lo = a; }
    { int a = lo, b = NATOMS; while (a < b) { int mid = (a + b) >> 1; if (bidx[mid] <= g) a = mid + 1; else b = mid; } hi = a; }
    int cnt = hi - lo;
    float4 sum = {0.f, 0.f, 0.f, 0.f};
    float4 mx = {-INFINITY, -INFINITY, -INFINITY, -INFINITY};
    for (int r = lo; r < hi; r++) {
        float4 v = unpack4(((const ushort4*)TOTAL)[(size_t)r * H4 + c4]);
        sum.x += v.x; sum.y += v.y; sum.z += v.z; sum.w += v.w;
        mx.x = fmaxf(mx.x, v.x); mx.y = fmaxf(mx.y, v.y);
        mx.z = fmaxf(mx.z, v.z); mx.w = fmaxf(mx.w, v.w);
    }
    float inv = 1.f / fmaxf((float)cnt, 1.f);
    if (cnt == 0) { mx.x = mx.y = mx.z = mx.w = 0.f; }
    float4 mean = {sum.x * inv, sum.y * inv, sum.z * inv, sum.w * inv};
    C4[(size_t)g * 576 + c4] = pack4(mean);
    C4[(size_t)g * 576 + 192 + c4] = pack4(sum);
    C4[(size_t)g * 576 + 384 + c4] = pack4(mx);
}

// ---------- last_hidden broadcast: out0[g][l][c] = HS[g][c] ----------
__global__ void bcast_k(const float* __restrict__ HS, float* __restrict__ out0)
{
    size_t idx = (size_t)blockIdx.x * 256 + threadIdx.x;   // over NG*LSEQ*H4
    int c4 = (int)(idx % H4);
    int g = (int)(idx / ((size_t)H4 * LSEQ));
    ((float4*)out0)[idx] = ((const float4*)HS)[(size_t)g * H4 + c4];
}

// ---------- recon gather: out2[n] = RECONG[bidx[n]] ----------
__global__ void recon_k(const float* __restrict__ RG, const int* __restrict__ bidx,
                        float* __restrict__ out2)
{
    size_t idx = (size_t)blockIdx.x * 256 + threadIdx.x;   // over NATOMS*16
    int n = (int)(idx >> 4), c4 = (int)(idx & 15);
    ((float4*)out2)[idx] = ((const float4*)RG)[(size_t)bidx[n] * 16 + c4];
}

extern "C" void kernel_launch(void* const* d_in, const int* in_sizes, int n_in,
                              void* d_out, int out_size, void* d_ws, size_t ws_size,
                              hipStream_t stream)
{
    const float* x    = (const float*)d_in[0];
    const int*   ei   = (const int*)d_in[1];
    const float* ea   = (const float*)d_in[2];
    const int*   bidx = (const int*)d_in[3];
    const float* Win  = (const float*)d_in[5];
    const float* bin  = (const float*)d_in[6];
    const float* bn0g = (const float*)d_in[7];
    const float* bn0b = (const float*)d_in[8];
    const float* bn0m = (const float*)d_in[9];
    const float* bn0v = (const float*)d_in[10];
    const float* Wc   = (const float*)d_in[11];
    const float* bc   = (const float*)d_in[12];
    const float* bncg = (const float*)d_in[13];
    const float* bncb = (const float*)d_in[14];
    const float* bncm = (const float*)d_in[15];
    const float* bncv = (const float*)d_in[16];
    const float* Ws   = (const float*)d_in[17];
    const float* bs   = (const float*)d_in[18];
    const float* bnsg = (const float*)d_in[19];
    const float* bnsb = (const float*)d_in[20];
    const float* bnsm = (const float*)d_in[21];
    const float* bnsv = (const float*)d_in[22];
    const float* Wp   = (const float*)d_in[23];
    const float* bp   = (const float*)d_in[24];
    const float* Wd1  = (const float*)d_in[25];
    const float* bd1  = (const float*)d_in[26];
    const float* bndg = (const float*)d_in[27];
    const float* bndb = (const float*)d_in[28];
    const float* bndm = (const float*)d_in[29];
    const float* bndv = (const float*)d_in[30];
    const float* Wd2  = (const float*)d_in[31];
    const float* bd2  = (const float*)d_in[32];

    float* out  = (float*)d_out;
    float* out0 = out;
    float* out1 = out + (size_t)NG * LSEQ * HDIM;
    float* out2 = out1 + (size_t)NG * HDIM;

    char* w = (char*)d_ws;
    size_t off = 0;
    auto alloc = [&](size_t bytes) { void* p = w + off; off += (bytes + 255) & ~255ULL; return p; };
    ushort* P      = (ushort*)alloc((size_t)NPAD * HDIM * 2);     // 46.2 MB
    ushort* TOTAL  = (ushort*)alloc((size_t)NATOMS * HDIM * 2);   // 46.1 MB
    ushort* HB     = (ushort*)alloc((size_t)NPAD * HDIM * 2);     // 46.2 MB
    ushort* XB     = (ushort*)alloc((size_t)NPAD * 64 * 2);       // 3.9 MB
    ushort* WT     = (ushort*)alloc((size_t)HDIM * 2304 * 2);     // 3.5 MB
    ushort* COMB   = (ushort*)alloc((size_t)GPAD * 2304 * 2);     // 3.0 MB
    float*  HS     = (float*) alloc((size_t)NG * HDIM * 4);
    ushort* HSB    = (ushort*)alloc((size_t)GPAD * HDIM * 2);
    ushort* POOLB  = (ushort*)alloc((size_t)GPAD * HDIM * 2);
    ushort* DGB    = (ushort*)alloc((size_t)GPAD * HDIM * 2);
    float*  RECONG = (float*) alloc((size_t)NG * 64 * 4);
    int*    cnt    = (int*)   alloc((size_t)NATOMS * 4);
    int*    row_off= (int*)   alloc((size_t)(NATOMS + 1) * 4);
    int*    cur    = (int*)   alloc((size_t)NATOMS * 4);
    int*    srcs   = (int*)   alloc((size_t)NEDGE * 4);
    float*  eas    = (float*) alloc((size_t)NEDGE * 8 * 4);       // 1.9 MB
    // peak ~155 MB

    const int* src_a = ei;
    const int* dst_a = ei + NEDGE;

    // input MLP via MFMA: XB = bf16(x); WinT; h0 = BN(relu(x@Win+bin)) -> HB and TOTAL
    cast_x_k<<<(NATOMS * 64 / 4) / 256, 256, 0, stream>>>(x, XB);
    transpose_cast_k<<<(HDIM * 64 + 255) / 256, 256, 0, stream>>>(Win, WT, 64, HDIM, HDIM);
    gemm_bt<1><<<dim3(NPAD / 128, HDIM / 128), 256, 0, stream>>>(
        XB, WT, nullptr, HB, TOTAL, bin, bn0g, bn0b, bn0m, bn0v, NATOMS, HDIM, 64);

    // CSR build (once; same edge list for all layers)
    zero_k<<<(NATOMS + 255) / 256, 256, 0, stream>>>(cnt, NATOMS);
    count_k<<<(NEDGE + 255) / 256, 256, 0, stream>>>(dst_a, cnt);
    scan_k<<<1, 1024, 0, stream>>>(cnt, row_off, cur);
    fill_k<<<(NEDGE + 255) / 256, 256, 0, stream>>>(src_a, dst_a, ea, cur, srcs, eas);

    // 3 conv layers
    for (int i = 0; i < 3; i++) {
        const float* Wci  = Wc + (size_t)i * 774 * HDIM;
        const float* Wcei = Wci + (size_t)HDIM * HDIM;     // rows 768..773
        const float* bci  = bc + i * HDIM;
        transpose_cast_k<<<(HDIM * HDIM + 255) / 256, 256, 0, stream>>>(Wci, WT, HDIM, HDIM, HDIM);
        gemm_bt<0><<<dim3(NPAD / 128, HDIM / 128), 256, 0, stream>>>(
            HB, WT, nullptr, P, nullptr, nullptr, nullptr, nullptr, nullptr, nullptr,
            NATOMS, HDIM, HDIM);
        node_agg_k<<<(NATOMS + NPN - 1) / NPN, 192, 0, stream>>>(
            P, row_off, srcs, eas, Wcei, bci,
            bncg + i * HDIM, bncb + i * HDIM, bncm + i * HDIM, bncv + i * HDIM, TOTAL, HB);
    }

    // pooling -> comb (bf16)
    pool_k<<<NG, 192, 0, stream>>>(TOTAL, bidx, COMB);

    // hs = BN(relu(comb @ Ws + bs))
    transpose_cast_k<<<(HDIM * 2304 + 255) / 256, 256, 0, stream>>>(Ws, WT, 2304, HDIM, HDIM);
    gemm_bt<1><<<dim3(GPAD / 128, HDIM / 128), 256, 0, stream>>>(
        COMB, WT, HS, HSB, nullptr, bs, bnsg, bnsb, bnsm, bnsv, NG, HDIM, 2304);

    // last_hidden broadcast
    bcast_k<<<(NG * LSEQ * H4) / 256, 256, 0, stream>>>(HS, out0);

    // pooler = tanh(hs @ Wp + bp)  -> out1
    transpose_cast_k<<<(HDIM * HDIM + 255) / 256, 256, 0, stream>>>(Wp, WT, HDIM, HDIM, HDIM);
    gemm_bt<2><<<dim3(GPAD / 128, HDIM / 128), 256, 0, stream>>>(
        HSB, WT, out1, POOLB, nullptr, bp, nullptr, nullptr, nullptr, nullptr, NG, HDIM, HDIM);

    // graph-level decoder: dg = BN(relu(pooler @ Wd1 + bd1))
    transpose_cast_k<<<(HDIM * HDIM + 255) / 256, 256, 0, stream>>>(Wd1, WT, HDIM, HDIM, HDIM);
    gemm_bt<1><<<dim3(GPAD / 128, HDIM / 128), 256, 0, stream>>>(
        POOLB, WT, nullptr, DGB, nullptr, bd1, bndg, bndb, bndm, bndv, NG, HDIM, HDIM);

    // recon_g = dg @ Wd2 + bd2  (N=64, padded to 128)
    transpose_cast_k<<<(128 * HDIM + 255) / 256, 256, 0, stream>>>(Wd2, WT, HDIM, 64, 128);
    gemm_bt<3><<<dim3(GPAD / 128, 1), 256, 0, stream>>>(
        DGB, WT, RECONG, nullptr, nullptr, bd2, nullptr, nullptr, nullptr, nullptr, NG, 64, HDIM);

    // expand recon to nodes
    recon_k<<<(NATOMS * 16) / 256, 256, 0, stream>>>(RECONG, bidx, out2);
}

// Round 7
// 804.929 us; speedup vs baseline: 3.3177x; 1.0623x over previous
//
#include <hip/hip_runtime.h>

#define NATOMS 30000
#define NPAD   30080        // 235*128
#define NEDGE  60000
#define HDIM   768
#define H4     192
#define NG     600
#define GPAD   640          // 5*128
#define LSEQ   20
#define BNEPS  1e-5f

typedef __attribute__((ext_vector_type(8))) short bf16x8;
typedef __attribute__((ext_vector_type(4))) float f32x4;

__device__ __forceinline__ ushort f2bf(float f) {
    union { float f; unsigned u; } v; v.f = f;
    unsigned r = v.u + 0x7FFFu + ((v.u >> 16) & 1u);
    return (ushort)(r >> 16);
}
__device__ __forceinline__ float bf2f(ushort u) {
    union { unsigned u; float f; } v; v.u = ((unsigned)u) << 16; return v.f;
}
__device__ __forceinline__ ushort4 pack4(float4 v) {
    ushort4 r; r.x = f2bf(v.x); r.y = f2bf(v.y); r.z = f2bf(v.z); r.w = f2bf(v.w); return r;
}
__device__ __forceinline__ float4 unpack4(ushort4 u) {
    float4 r; r.x = bf2f(u.x); r.y = bf2f(u.y); r.z = bf2f(u.z); r.w = bf2f(u.w); return r;
}
// async global->LDS, 16B per lane; LDS dest wave-uniform base + lane*16, global src per-lane
__device__ __forceinline__ void gl_lds16(const ushort* g, ushort* l) {
    __builtin_amdgcn_global_load_lds(
        (const __attribute__((address_space(1))) void*)(g),
        (__attribute__((address_space(3))) void*)(l), 16, 0, 0);
}

// ---------- fused prep: all weight transposes + x cast + cnt zero (1 launch) ----------
// segment sizes (items)
#define PC0 (3L*768*768)            // convT
#define PC1 (PC0 + 768L*64)         // WinT
#define PC2 (PC1 + 768L*2304)       // WsT
#define PC3 (PC2 + 768L*768)        // WpT
#define PC4 (PC3 + 768L*768)        // Wd1T
#define PC5 (PC4 + 128L*768)        // Wd2T
#define PC6 (PC5 + 480000L)         // XB (float4 units = NATOMS*64/4)
#define PC7 (PC6 + NATOMS)          // cnt zero
__global__ __launch_bounds__(256) void prep_k(
    const float* __restrict__ Wc, const float* __restrict__ Win, const float* __restrict__ Ws,
    const float* __restrict__ Wp, const float* __restrict__ Wd1, const float* __restrict__ Wd2,
    const float* __restrict__ x,
    ushort* __restrict__ WTc, ushort* __restrict__ WinT, ushort* __restrict__ WsT,
    ushort* __restrict__ WpT, ushort* __restrict__ Wd1T, ushort* __restrict__ Wd2T,
    ushort* __restrict__ XB, int* __restrict__ cnt)
{
    long idx = (long)blockIdx.x * 256 + threadIdx.x;
    if (idx < PC0) {
        long b = idx / (768 * 768), rem = idx % (768 * 768);
        long n = rem / 768, k = rem % 768;
        WTc[idx] = f2bf(Wc[b * 594432 + k * 768 + n]);          // Wc: [3][774][768]
    } else if (idx < PC1) {
        long j = idx - PC0; long n = j / 64, k = j % 64;
        WinT[j] = f2bf(Win[k * 768 + n]);
    } else if (idx < PC2) {
        long j = idx - PC1; long n = j / 2304, k = j % 2304;
        WsT[j] = f2bf(Ws[k * 768 + n]);
    } else if (idx < PC3) {
        long j = idx - PC2; long n = j / 768, k = j % 768;
        WpT[j] = f2bf(Wp[k * 768 + n]);
    } else if (idx < PC4) {
        long j = idx - PC3; long n = j / 768, k = j % 768;
        Wd1T[j] = f2bf(Wd1[k * 768 + n]);
    } else if (idx < PC5) {
        long j = idx - PC4; long n = j / 768, k = j % 768;
        Wd2T[j] = (n < 64) ? f2bf(Wd2[k * 64 + n]) : (ushort)0;  // Wd2: [768][64]
    } else if (idx < PC6) {
        long j = idx - PC5;
        ((ushort4*)XB)[j] = pack4(((const float4*)x)[j]);
    } else if (idx < PC7) {
        cnt[idx - PC6] = 0;
    }
}

// ---------- bf16 MFMA GEMM (m97-style global_load_lds staging, linear LDS [128][32]) ----------
// C = A[.][K] @ Bt[.][K]^T ; EPI: 0=none, 1=bias+relu+BN, 2=bias+tanh, 3=bias
// SWZ=1: 1-D grid, bcol-fast + bijective chunked XCD swizzle (each XCD owns contiguous rows)
template <int EPI, int SWZ>
__global__ __launch_bounds__(256) void gemm_bt(
    const ushort* __restrict__ A, const ushort* __restrict__ Bt,
    float* __restrict__ Cf, ushort* __restrict__ Cb, ushort* __restrict__ Cb2,
    const float* __restrict__ bias,
    const float* __restrict__ bng, const float* __restrict__ bnb,
    const float* __restrict__ bnm, const float* __restrict__ bnv,
    int Mreal, int Nreal, int K, int nbx)
{
    __shared__ ushort As[128 * 32];
    __shared__ ushort Bs[128 * 32];
    int t = threadIdx.x;
    int lane = t & 63, wave = t >> 6;
    int wr = wave >> 1, wc = wave & 1;
    int brow, bcol;
    if (SWZ) {
        int nwg = gridDim.x;
        int q = nwg >> 3, r = nwg & 7;
        int id = blockIdx.x;
        int xcd = id & 7, i = id >> 3;
        int s = (xcd < r) ? xcd * (q + 1) + i : r * (q + 1) + (xcd - r) * q + i;
        bcol = s % 6; brow = s / 6;           // SWZ path: nbx fixed = 6
    } else {
        bcol = blockIdx.x; brow = blockIdx.y;
    }

    f32x4 acc[4][4];
    #pragma unroll
    for (int i = 0; i < 4; i++)
        #pragma unroll
        for (int j = 0; j < 4; j++) acc[i][j] = (f32x4)0.f;

    // staging: wave w covers LDS chunks {2w,2w+1} of A and B (1 KB each)
    const int r0 = wave * 32 + (lane >> 2);
    const int ce = (lane & 3) * 8;
    const ushort* Ag0 = A + (size_t)(brow * 128 + r0) * K + ce;
    const ushort* Ag1 = A + (size_t)(brow * 128 + r0 + 16) * K + ce;
    const ushort* Bg0 = Bt + (size_t)(bcol * 128 + r0) * K + ce;
    const ushort* Bg1 = Bt + (size_t)(bcol * 128 + r0 + 16) * K + ce;
    ushort* Al0 = As + wave * 1024;
    ushort* Al1 = As + wave * 1024 + 512;
    ushort* Bl0 = Bs + wave * 1024;
    ushort* Bl1 = Bs + wave * 1024 + 512;

    const int lr = lane & 15, lk = (lane >> 4) * 8;

    for (int kt = 0; kt < K; kt += 32) {
        __syncthreads();
        gl_lds16(Ag0 + kt, Al0);
        gl_lds16(Ag1 + kt, Al1);
        gl_lds16(Bg0 + kt, Bl0);
        gl_lds16(Bg1 + kt, Bl1);
        __syncthreads();

        bf16x8 af[4], bfr[4];
        #pragma unroll
        for (int mf = 0; mf < 4; mf++)
            af[mf] = *(const bf16x8*)(&As[(wr * 64 + mf * 16 + lr) * 32 + lk]);
        #pragma unroll
        for (int nf = 0; nf < 4; nf++)
            bfr[nf] = *(const bf16x8*)(&Bs[(wc * 64 + nf * 16 + lr) * 32 + lk]);
        #pragma unroll
        for (int mf = 0; mf < 4; mf++)
            #pragma unroll
            for (int nf = 0; nf < 4; nf++)
                acc[mf][nf] = __builtin_amdgcn_mfma_f32_16x16x32_bf16(af[mf], bfr[nf], acc[mf][nf], 0, 0, 0);
    }

    const int lq = lane >> 4;
    #pragma unroll
    for (int mf = 0; mf < 4; mf++) {
        #pragma unroll
        for (int nf = 0; nf < 4; nf++) {
            int col = bcol * 128 + wc * 64 + nf * 16 + lr;
            #pragma unroll
            for (int rg = 0; rg < 4; rg++) {
                int row = brow * 128 + wr * 64 + mf * 16 + lq * 4 + rg;
                if (row < Mreal && col < Nreal) {
                    float v = acc[mf][nf][rg];
                    if (EPI >= 1) v += bias[col];
                    if (EPI == 1) {
                        v = fmaxf(v, 0.f);
                        float s = bng[col] * rsqrtf(bnv[col] + BNEPS);
                        v = (v - bnm[col]) * s + bnb[col];
                    } else if (EPI == 2) {
                        v = tanhf(v);
                    }
                    size_t o = (size_t)row * Nreal + col;
                    if (Cf) Cf[o] = v;
                    if (Cb) Cb[o] = f2bf(v);
                    if (Cb2) Cb2[o] = f2bf(v);
                }
            }
        }
    }
}

// ================= CSR build (once; shared by all 3 conv layers) =================

__global__ void count_k(const int* __restrict__ dst_a, int* __restrict__ cnt)
{
    int e = blockIdx.x * 256 + threadIdx.x;
    if (e < NEDGE) atomicAdd(&cnt[dst_a[e]], 1);
}

__global__ __launch_bounds__(1024) void scan_k(const int* __restrict__ cnt,
                                               int* __restrict__ row_off,
                                               int* __restrict__ cur)
{
    __shared__ int part[1024];
    const int CH = (NATOMS + 1023) / 1024;
    int t = threadIdx.x;
    int base = t * CH;
    int s = 0;
    for (int i = base; i < base + CH && i < NATOMS; i++) s += cnt[i];
    part[t] = s;
    __syncthreads();
    for (int off = 1; off < 1024; off <<= 1) {
        int v = (t >= off) ? part[t - off] : 0;
        __syncthreads();
        part[t] += v;
        __syncthreads();
    }
    int excl = part[t] - s;
    for (int i = base; i < base + CH && i < NATOMS; i++) {
        row_off[i] = excl;
        cur[i] = excl;
        excl += cnt[i];
    }
    if (t == 1023) row_off[NATOMS] = part[1023];
}

__global__ void fill_k(const int* __restrict__ src_a, const int* __restrict__ dst_a,
                       const float* __restrict__ ea,
                       int* __restrict__ cur, int* __restrict__ srcs, float* __restrict__ eas)
{
    int e = blockIdx.x * 256 + threadIdx.x;
    if (e >= NEDGE) return;
    int d = dst_a[e];
    int pos = atomicAdd(&cur[d], 1);
    srcs[pos] = src_a[e];
    float* o = eas + (size_t)pos * 8;
    o[0] = ea[e * 6 + 0]; o[1] = ea[e * 6 + 1]; o[2] = ea[e * 6 + 2];
    o[3] = ea[e * 6 + 3]; o[4] = ea[e * 6 + 4]; o[5] = ea[e * 6 + 5];
}

// ---------- fused per-node aggregation (4 nodes/block): self-loop + edges + BN + TOTAL + HB ----------
#define NPN 4
__global__ __launch_bounds__(192) void node_agg_k(
    const ushort* __restrict__ P, const int* __restrict__ row_off,
    const int* __restrict__ srcs, const float* __restrict__ eas,
    const float* __restrict__ Wce, const float* __restrict__ bc,
    const float* __restrict__ g, const float* __restrict__ b,
    const float* __restrict__ m, const float* __restrict__ vv,
    ushort* __restrict__ TOTAL, ushort* __restrict__ HB)
{
    int n0 = blockIdx.x * NPN;
    int c4 = threadIdx.x;
    const float4* W4 = (const float4*)Wce;
    float4 w0 = W4[0 * H4 + c4], w1 = W4[1 * H4 + c4], w2 = W4[2 * H4 + c4];
    float4 w3 = W4[3 * H4 + c4], w4 = W4[4 * H4 + c4], w5 = W4[5 * H4 + c4];
    float4 bb = ((const float4*)bc)[c4];
    float4 gg = ((const float4*)g)[c4], bo = ((const float4*)b)[c4];
    float4 mm = ((const float4*)m)[c4], vq = ((const float4*)vv)[c4];
    float4 sc;
    sc.x = gg.x * rsqrtf(vq.x + BNEPS); sc.y = gg.y * rsqrtf(vq.y + BNEPS);
    sc.z = gg.z * rsqrtf(vq.z + BNEPS); sc.w = gg.w * rsqrtf(vq.w + BNEPS);

    for (int u = 0; u < NPN; u++) {
        int n = n0 + u;
        if (n >= NATOMS) return;
        float4 p = unpack4(((const ushort4*)P)[(size_t)n * H4 + c4]);
        float4 acc;
        acc.x = fmaxf(p.x + bb.x, 0.f); acc.y = fmaxf(p.y + bb.y, 0.f);
        acc.z = fmaxf(p.z + bb.z, 0.f); acc.w = fmaxf(p.w + bb.w, 0.f);

        int lo = row_off[n], hi = row_off[n + 1];
        for (int j = lo; j < hi; j++) {
            int s = srcs[j];
            const float* e8 = eas + (size_t)j * 8;
            float4 eA = *(const float4*)(e8);
            float e4v = e8[4], e5v = e8[5];
            float4 ps = unpack4(((const ushort4*)P)[(size_t)s * H4 + c4]);
            float4 v;
            v.x = fmaxf(ps.x + eA.x * w0.x + eA.y * w1.x + eA.z * w2.x + eA.w * w3.x + e4v * w4.x + e5v * w5.x + bb.x, 0.f);
            v.y = fmaxf(ps.y + eA.x * w0.y + eA.y * w1.y + eA.z * w2.y + eA.w * w3.y + e4v * w4.y + e5v * w5.y + bb.y, 0.f);
            v.z = fmaxf(ps.z + eA.x * w0.z + eA.y * w1.z + eA.z * w2.z + eA.w * w3.z + e4v * w4.z + e5v * w5.z + bb.z, 0.f);
            v.w = fmaxf(ps.w + eA.x * w0.w + eA.y * w1.w + eA.z * w2.w + eA.w * w3.w + e4v * w4.w + e5v * w5.w + bb.w, 0.f);
            acc.x += v.x; acc.y += v.y; acc.z += v.z; acc.w += v.w;
        }

        float4 hv;
        hv.x = (acc.x - mm.x) * sc.x + bo.x;
        hv.y = (acc.y - mm.y) * sc.y + bo.y;
        hv.z = (acc.z - mm.z) * sc.z + bo.z;
        hv.w = (acc.w - mm.w) * sc.w + bo.w;
        size_t idx = (size_t)n * H4 + c4;
        float4 tt = unpack4(((const ushort4*)TOTAL)[idx]);
        tt.x += hv.x; tt.y += hv.y; tt.z += hv.z; tt.w += hv.w;
        ((ushort4*)TOTAL)[idx] = pack4(tt);
        ((ushort4*)HB)[idx] = pack4(hv);
    }
}

// ---------- per-graph pooling -> COMB bf16 [GPAD][2304] = [mean | add | max] ----------
// grid (NG, 3), 64 threads: each lane owns one c4 chunk
__global__ __launch_bounds__(64) void pool_k(const ushort* __restrict__ TOTAL,
                                             const int* __restrict__ bidx,
                                             ushort* __restrict__ COMB)
{
    int g = blockIdx.x;
    int c4 = blockIdx.y * 64 + threadIdx.x;
    ushort4* C4 = (ushort4*)COMB;
    int lo, hi;
    { int a = 0, b = NATOMS; while (a < b) { int mid = (a + b) >> 1; if (bidx[mid] < g) a = mid + 1; else b = mid; } lo = a; }
    { int a = lo, b = NATOMS; while (a < b) { int mid = (a + b) >> 1; if (bidx[mid] <= g) a = mid + 1; else b = mid; } hi = a; }
    int cnt = hi - lo;
    float4 sum = {0.f, 0.f, 0.f, 0.f};
    float4 mx = {-INFINITY, -INFINITY, -INFINITY, -INFINITY};
    for (int r = lo; r < hi; r++) {
        float4 v = unpack4(((const ushort4*)TOTAL)[(size_t)r * H4 + c4]);
        sum.x += v.x; sum.y += v.y; sum.z += v.z; sum.w += v.w;
        mx.x = fmaxf(mx.x, v.x); mx.y = fmaxf(mx.y, v.y);
        mx.z = fmaxf(mx.z, v.z); mx.w = fmaxf(mx.w, v.w);
    }
    float inv = 1.f / fmaxf((float)cnt, 1.f);
    if (cnt == 0) { mx.x = mx.y = mx.z = mx.w = 0.f; }
    float4 mean = {sum.x * inv, sum.y * inv, sum.z * inv, sum.w * inv};
    C4[(size_t)g * 576 + c4] = pack4(mean);
    C4[(size_t)g * 576 + 192 + c4] = pack4(sum);
    C4[(size_t)g * 576 + 384 + c4] = pack4(mx);
}

// ---------- last_hidden broadcast ----------
__global__ void bcast_k(const float* __restrict__ HS, float* __restrict__ out0)
{
    size_t idx = (size_t)blockIdx.x * 256 + threadIdx.x;   // over NG*LSEQ*H4
    int c4 = (int)(idx % H4);
    int g = (int)(idx / ((size_t)H4 * LSEQ));
    ((float4*)out0)[idx] = ((const float4*)HS)[(size_t)g * H4 + c4];
}

// ---------- recon gather ----------
__global__ void recon_k(const float* __restrict__ RG, const int* __restrict__ bidx,
                        float* __restrict__ out2)
{
    size_t idx = (size_t)blockIdx.x * 256 + threadIdx.x;   // over NATOMS*16
    int n = (int)(idx >> 4), c4 = (int)(idx & 15);
    ((float4*)out2)[idx] = ((const float4*)RG)[(size_t)bidx[n] * 16 + c4];
}

extern "C" void kernel_launch(void* const* d_in, const int* in_sizes, int n_in,
                              void* d_out, int out_size, void* d_ws, size_t ws_size,
                              hipStream_t stream)
{
    const float* x    = (const float*)d_in[0];
    const int*   ei   = (const int*)d_in[1];
    const float* ea   = (const float*)d_in[2];
    const int*   bidx = (const int*)d_in[3];
    const float* Win  = (const float*)d_in[5];
    const float* bin  = (const float*)d_in[6];
    const float* bn0g = (const float*)d_in[7];
    const float* bn0b = (const float*)d_in[8];
    const float* bn0m = (const float*)d_in[9];
    const float* bn0v = (const float*)d_in[10];
    const float* Wc   = (const float*)d_in[11];
    const float* bc   = (const float*)d_in[12];
    const float* bncg = (const float*)d_in[13];
    const float* bncb = (const float*)d_in[14];
    const float* bncm = (const float*)d_in[15];
    const float* bncv = (const float*)d_in[16];
    const float* Ws   = (const float*)d_in[17];
    const float* bs   = (const float*)d_in[18];
    const float* bnsg = (const float*)d_in[19];
    const float* bnsb = (const float*)d_in[20];
    const float* bnsm = (const float*)d_in[21];
    const float* bnsv = (const float*)d_in[22];
    const float* Wp   = (const float*)d_in[23];
    const float* bp   = (const float*)d_in[24];
    const float* Wd1  = (const float*)d_in[25];
    const float* bd1  = (const float*)d_in[26];
    const float* bndg = (const float*)d_in[27];
    const float* bndb = (const float*)d_in[28];
    const float* bndm = (const float*)d_in[29];
    const float* bndv = (const float*)d_in[30];
    const float* Wd2  = (const float*)d_in[31];
    const float* bd2  = (const float*)d_in[32];

    float* out  = (float*)d_out;
    float* out0 = out;
    float* out1 = out + (size_t)NG * LSEQ * HDIM;
    float* out2 = out1 + (size_t)NG * HDIM;

    char* w = (char*)d_ws;
    size_t off = 0;
    auto alloc = [&](size_t bytes) { void* p = w + off; off += (bytes + 255) & ~255ULL; return p; };
    ushort* P      = (ushort*)alloc((size_t)NPAD * HDIM * 2);     // 46.2 MB
    ushort* TOTAL  = (ushort*)alloc((size_t)NATOMS * HDIM * 2);   // 46.1 MB
    ushort* HB     = (ushort*)alloc((size_t)NPAD * HDIM * 2);     // 46.2 MB
    ushort* XB     = (ushort*)alloc((size_t)NPAD * 64 * 2);       // 3.9 MB
    ushort* WTc    = (ushort*)alloc((size_t)3 * 768 * 768 * 2);   // 3.5 MB
    ushort* WinT   = (ushort*)alloc((size_t)768 * 64 * 2);
    ushort* WsT    = (ushort*)alloc((size_t)768 * 2304 * 2);      // 3.5 MB
    ushort* WpT    = (ushort*)alloc((size_t)768 * 768 * 2);
    ushort* Wd1T   = (ushort*)alloc((size_t)768 * 768 * 2);
    ushort* Wd2T   = (ushort*)alloc((size_t)128 * 768 * 2);
    ushort* COMB   = (ushort*)alloc((size_t)GPAD * 2304 * 2);     // 3.0 MB
    float*  HS     = (float*) alloc((size_t)NG * HDIM * 4);
    ushort* HSB    = (ushort*)alloc((size_t)GPAD * HDIM * 2);
    ushort* POOLB  = (ushort*)alloc((size_t)GPAD * HDIM * 2);
    ushort* DGB    = (ushort*)alloc((size_t)GPAD * HDIM * 2);
    float*  RECONG = (float*) alloc((size_t)NG * 64 * 4);
    int*    cnt    = (int*)   alloc((size_t)NATOMS * 4);
    int*    row_off= (int*)   alloc((size_t)(NATOMS + 1) * 4);
    int*    cur    = (int*)   alloc((size_t)NATOMS * 4);
    int*    srcs   = (int*)   alloc((size_t)NEDGE * 4);
    float*  eas    = (float*) alloc((size_t)NEDGE * 8 * 4);       // 1.9 MB
    // peak ~163 MB

    const int* src_a = ei;
    const int* dst_a = ei + NEDGE;

    // 1 launch: all weight transposes + x cast + cnt zero
    prep_k<<<(int)((PC7 + 255) / 256), 256, 0, stream>>>(
        Wc, Win, Ws, Wp, Wd1, Wd2, x, WTc, WinT, WsT, WpT, Wd1T, Wd2T, XB, cnt);

    // CSR build
    count_k<<<(NEDGE + 255) / 256, 256, 0, stream>>>(dst_a, cnt);
    scan_k<<<1, 1024, 0, stream>>>(cnt, row_off, cur);
    fill_k<<<(NEDGE + 255) / 256, 256, 0, stream>>>(src_a, dst_a, ea, cur, srcs, eas);

    // input MLP via MFMA: h0 = BN(relu(x@Win+bin)) -> HB and TOTAL
    gemm_bt<1, 1><<<1410, 256, 0, stream>>>(
        XB, WinT, nullptr, HB, TOTAL, bin, bn0g, bn0b, bn0m, bn0v, NATOMS, HDIM, 64, 6);

    // 3 conv layers
    for (int i = 0; i < 3; i++) {
        const float* Wcei = Wc + (size_t)i * 774 * HDIM + (size_t)HDIM * HDIM;  // rows 768..773
        const float* bci  = bc + i * HDIM;
        gemm_bt<0, 1><<<1410, 256, 0, stream>>>(
            HB, WTc + (size_t)i * 768 * 768, nullptr, P, nullptr,
            nullptr, nullptr, nullptr, nullptr, nullptr, NATOMS, HDIM, HDIM, 6);
        node_agg_k<<<(NATOMS + NPN - 1) / NPN, 192, 0, stream>>>(
            P, row_off, srcs, eas, Wcei, bci,
            bncg + i * HDIM, bncb + i * HDIM, bncm + i * HDIM, bncv + i * HDIM, TOTAL, HB);
    }

    // pooling -> comb (bf16)
    pool_k<<<dim3(NG, 3), 64, 0, stream>>>(TOTAL, bidx, COMB);

    // hs = BN(relu(comb @ Ws + bs))
    gemm_bt<1, 0><<<dim3(6, 5), 256, 0, stream>>>(
        COMB, WsT, HS, HSB, nullptr, bs, bnsg, bnsb, bnsm, bnsv, NG, HDIM, 2304, 6);

    // last_hidden broadcast
    bcast_k<<<(NG * LSEQ * H4) / 256, 256, 0, stream>>>(HS, out0);

    // pooler = tanh(hs @ Wp + bp) -> out1
    gemm_bt<2, 0><<<dim3(6, 5), 256, 0, stream>>>(
        HSB, WpT, out1, POOLB, nullptr, bp, nullptr, nullptr, nullptr, nullptr, NG, HDIM, HDIM, 6);

    // dg = BN(relu(pooler @ Wd1 + bd1))
    gemm_bt<1, 0><<<dim3(6, 5), 256, 0, stream>>>(
        POOLB, Wd1T, nullptr, DGB, nullptr, bd1, bndg, bndb, bndm, bndv, NG, HDIM, HDIM, 6);

    // recon_g = dg @ Wd2 + bd2  (N=64)
    gemm_bt<3, 0><<<dim3(1, 5), 256, 0, stream>>>(
        DGB, Wd2T, RECONG, nullptr, nullptr, bd2, nullptr, nullptr, nullptr, nullptr, NG, 64, HDIM, 1);

    // expand recon to nodes
    recon_k<<<(NATOMS * 16) / 256, 256, 0, stream>>>(RECONG, bidx, out2);
}

// Round 8
// 771.733 us; speedup vs baseline: 3.4604x; 1.0430x over previous
//
#include <hip/hip_runtime.h>

#define NATOMS 30000
#define NPAD   30080        // 235*128
#define NEDGE  60000
#define HDIM   768
#define H4     192
#define NG     600
#define GPAD   640          // 5*128
#define LSEQ   20
#define BNEPS  1e-5f

typedef __attribute__((ext_vector_type(8))) short bf16x8;
typedef __attribute__((ext_vector_type(4))) float f32x4;

__device__ __forceinline__ ushort f2bf(float f) {
    union { float f; unsigned u; } v; v.f = f;
    unsigned r = v.u + 0x7FFFu + ((v.u >> 16) & 1u);
    return (ushort)(r >> 16);
}
__device__ __forceinline__ float bf2f(ushort u) {
    union { unsigned u; float f; } v; v.u = ((unsigned)u) << 16; return v.f;
}
__device__ __forceinline__ ushort4 pack4(float4 v) {
    ushort4 r; r.x = f2bf(v.x); r.y = f2bf(v.y); r.z = f2bf(v.z); r.w = f2bf(v.w); return r;
}
__device__ __forceinline__ float4 unpack4(ushort4 u) {
    float4 r; r.x = bf2f(u.x); r.y = bf2f(u.y); r.z = bf2f(u.z); r.w = bf2f(u.w); return r;
}
// async global->LDS, 16B per lane; LDS dest wave-uniform base + lane*16, global src per-lane
__device__ __forceinline__ void gl_lds16(const ushort* g, ushort* l) {
    __builtin_amdgcn_global_load_lds(
        (const __attribute__((address_space(1))) void*)(g),
        (__attribute__((address_space(3))) void*)(l), 16, 0, 0);
}

// ---------- fused prep: all weight transposes + x cast + cnt zero (1 launch) ----------
#define PC0 (3L*768*768)            // convT
#define PC1 (PC0 + 768L*64)         // WinT
#define PC2 (PC1 + 768L*2304)       // WsT
#define PC3 (PC2 + 768L*768)        // WpT
#define PC4 (PC3 + 768L*768)        // Wd1T
#define PC5 (PC4 + 128L*768)        // Wd2T
#define PC6 (PC5 + 480000L)         // XB (float4 units = NATOMS*64/4)
#define PC7 (PC6 + NATOMS)          // cnt zero
__global__ __launch_bounds__(256) void prep_k(
    const float* __restrict__ Wc, const float* __restrict__ Win, const float* __restrict__ Ws,
    const float* __restrict__ Wp, const float* __restrict__ Wd1, const float* __restrict__ Wd2,
    const float* __restrict__ x,
    ushort* __restrict__ WTc, ushort* __restrict__ WinT, ushort* __restrict__ WsT,
    ushort* __restrict__ WpT, ushort* __restrict__ Wd1T, ushort* __restrict__ Wd2T,
    ushort* __restrict__ XB, int* __restrict__ cnt)
{
    long idx = (long)blockIdx.x * 256 + threadIdx.x;
    if (idx < PC0) {
        long b = idx / (768 * 768), rem = idx % (768 * 768);
        long n = rem / 768, k = rem % 768;
        WTc[idx] = f2bf(Wc[b * 594432 + k * 768 + n]);          // Wc: [3][774][768]
    } else if (idx < PC1) {
        long j = idx - PC0; long n = j / 64, k = j % 64;
        WinT[j] = f2bf(Win[k * 768 + n]);
    } else if (idx < PC2) {
        long j = idx - PC1; long n = j / 2304, k = j % 2304;
        WsT[j] = f2bf(Ws[k * 768 + n]);
    } else if (idx < PC3) {
        long j = idx - PC2; long n = j / 768, k = j % 768;
        WpT[j] = f2bf(Wp[k * 768 + n]);
    } else if (idx < PC4) {
        long j = idx - PC3; long n = j / 768, k = j % 768;
        Wd1T[j] = f2bf(Wd1[k * 768 + n]);
    } else if (idx < PC5) {
        long j = idx - PC4; long n = j / 768, k = j % 768;
        Wd2T[j] = (n < 64) ? f2bf(Wd2[k * 64 + n]) : (ushort)0;  // Wd2: [768][64]
    } else if (idx < PC6) {
        long j = idx - PC5;
        ((ushort4*)XB)[j] = pack4(((const float4*)x)[j]);
    } else if (idx < PC7) {
        cnt[idx - PC6] = 0;
    }
}

// ---------- bf16 MFMA GEMM: 2-phase double-buffered global_load_lds staging ----------
// C = A[.][K] @ Bt[.][K]^T ; EPI: 0=none, 1=bias+relu+BN, 2=bias+tanh, 3=bias
// SWZ=1: 1-D grid, bcol-fast + bijective chunked XCD swizzle
template <int EPI, int SWZ>
__global__ __launch_bounds__(256) void gemm_bt(
    const ushort* __restrict__ A, const ushort* __restrict__ Bt,
    float* __restrict__ Cf, ushort* __restrict__ Cb, ushort* __restrict__ Cb2,
    const float* __restrict__ bias,
    const float* __restrict__ bng, const float* __restrict__ bnb,
    const float* __restrict__ bnm, const float* __restrict__ bnv,
    int Mreal, int Nreal, int K, int nbx)
{
    __shared__ ushort As[2][128 * 32];
    __shared__ ushort Bs[2][128 * 32];
    int t = threadIdx.x;
    int lane = t & 63, wave = t >> 6;
    int wr = wave >> 1, wc = wave & 1;
    int brow, bcol;
    if (SWZ) {
        int nwg = gridDim.x;
        int q = nwg >> 3, r = nwg & 7;
        int id = blockIdx.x;
        int xcd = id & 7, i = id >> 3;
        int s = (xcd < r) ? xcd * (q + 1) + i : r * (q + 1) + (xcd - r) * q + i;
        bcol = s % 6; brow = s / 6;           // SWZ path: nbx fixed = 6
    } else {
        bcol = blockIdx.x; brow = blockIdx.y;
    }

    f32x4 acc[4][4];
    #pragma unroll
    for (int i = 0; i < 4; i++)
        #pragma unroll
        for (int j = 0; j < 4; j++) acc[i][j] = (f32x4)0.f;

    // staging: wave w covers LDS chunks {2w,2w+1} of A and B (1 KB each)
    const int r0 = wave * 32 + (lane >> 2);
    const int ce = (lane & 3) * 8;
    const ushort* Ag0 = A + (size_t)(brow * 128 + r0) * K + ce;
    const ushort* Ag1 = A + (size_t)(brow * 128 + r0 + 16) * K + ce;
    const ushort* Bg0 = Bt + (size_t)(bcol * 128 + r0) * K + ce;
    const ushort* Bg1 = Bt + (size_t)(bcol * 128 + r0 + 16) * K + ce;
    const int wo = wave * 1024;

    const int lr = lane & 15, lk = (lane >> 4) * 8;

    // prologue: stage tile 0 into buf 0, drain, barrier
    gl_lds16(Ag0, &As[0][wo]);
    gl_lds16(Ag1, &As[0][wo + 512]);
    gl_lds16(Bg0, &Bs[0][wo]);
    gl_lds16(Bg1, &Bs[0][wo + 512]);
    __syncthreads();                            // drains vmcnt(0) + barrier

    int cur = 0;
    for (int kt = 0; kt < K; kt += 32) {
        // issue NEXT tile's loads into the other buffer (in flight under compute)
        if (kt + 32 < K) {
            int nb = cur ^ 1;
            gl_lds16(Ag0 + kt + 32, &As[nb][wo]);
            gl_lds16(Ag1 + kt + 32, &As[nb][wo + 512]);
            gl_lds16(Bg0 + kt + 32, &Bs[nb][wo]);
            gl_lds16(Bg1 + kt + 32, &Bs[nb][wo + 512]);
        }

        bf16x8 af[4], bfr[4];
        #pragma unroll
        for (int mf = 0; mf < 4; mf++)
            af[mf] = *(const bf16x8*)(&As[cur][(wr * 64 + mf * 16 + lr) * 32 + lk]);
        #pragma unroll
        for (int nf = 0; nf < 4; nf++)
            bfr[nf] = *(const bf16x8*)(&Bs[cur][(wc * 64 + nf * 16 + lr) * 32 + lk]);
        #pragma unroll
        for (int mf = 0; mf < 4; mf++)
            #pragma unroll
            for (int nf = 0; nf < 4; nf++)
                acc[mf][nf] = __builtin_amdgcn_mfma_f32_16x16x32_bf16(af[mf], bfr[nf], acc[mf][nf], 0, 0, 0);

        __syncthreads();       // drains prefetch vmcnt(0) (overlapped by MFMA) + protects swap
        cur ^= 1;
    }

    const int lq = lane >> 4;
    #pragma unroll
    for (int mf = 0; mf < 4; mf++) {
        #pragma unroll
        for (int nf = 0; nf < 4; nf++) {
            int col = bcol * 128 + wc * 64 + nf * 16 + lr;
            #pragma unroll
            for (int rg = 0; rg < 4; rg++) {
                int row = brow * 128 + wr * 64 + mf * 16 + lq * 4 + rg;
                if (row < Mreal && col < Nreal) {
                    float v = acc[mf][nf][rg];
                    if (EPI >= 1) v += bias[col];
                    if (EPI == 1) {
                        v = fmaxf(v, 0.f);
                        float s = bng[col] * rsqrtf(bnv[col] + BNEPS);
                        v = (v - bnm[col]) * s + bnb[col];
                    } else if (EPI == 2) {
                        v = tanhf(v);
                    }
                    size_t o = (size_t)row * Nreal + col;
                    if (Cf) Cf[o] = v;
                    if (Cb) Cb[o] = f2bf(v);
                    if (Cb2) Cb2[o] = f2bf(v);
                }
            }
        }
    }
}

// ================= CSR build (once; shared by all 3 conv layers) =================

__global__ void count_k(const int* __restrict__ dst_a, int* __restrict__ cnt)
{
    int e = blockIdx.x * 256 + threadIdx.x;
    if (e < NEDGE) atomicAdd(&cnt[dst_a[e]], 1);
}

__global__ __launch_bounds__(1024) void scan_k(const int* __restrict__ cnt,
                                               int* __restrict__ row_off,
                                               int* __restrict__ cur)
{
    __shared__ int part[1024];
    const int CH = (NATOMS + 1023) / 1024;
    int t = threadIdx.x;
    int base = t * CH;
    int s = 0;
    for (int i = base; i < base + CH && i < NATOMS; i++) s += cnt[i];
    part[t] = s;
    __syncthreads();
    for (int off = 1; off < 1024; off <<= 1) {
        int v = (t >= off) ? part[t - off] : 0;
        __syncthreads();
        part[t] += v;
        __syncthreads();
    }
    int excl = part[t] - s;
    for (int i = base; i < base + CH && i < NATOMS; i++) {
        row_off[i] = excl;
        cur[i] = excl;
        excl += cnt[i];
    }
    if (t == 1023) row_off[NATOMS] = part[1023];
}

__global__ void fill_k(const int* __restrict__ src_a, const int* __restrict__ dst_a,
                       const float* __restrict__ ea,
                       int* __restrict__ cur, int* __restrict__ srcs, float* __restrict__ eas)
{
    int e = blockIdx.x * 256 + threadIdx.x;
    if (e >= NEDGE) return;
    int d = dst_a[e];
    int pos = atomicAdd(&cur[d], 1);
    srcs[pos] = src_a[e];
    float* o = eas + (size_t)pos * 8;
    o[0] = ea[e * 6 + 0]; o[1] = ea[e * 6 + 1]; o[2] = ea[e * 6 + 2];
    o[3] = ea[e * 6 + 3]; o[4] = ea[e * 6 + 4]; o[5] = ea[e * 6 + 5];
}

// ---------- fused per-node aggregation (8 nodes/block): self-loop + edges + BN + TOTAL + HB ----------
#define NPN 8
__global__ __launch_bounds__(192) void node_agg_k(
    const ushort* __restrict__ P, const int* __restrict__ row_off,
    const int* __restrict__ srcs, const float* __restrict__ eas,
    const float* __restrict__ Wce, const float* __restrict__ bc,
    const float* __restrict__ g, const float* __restrict__ b,
    const float* __restrict__ m, const float* __restrict__ vv,
    ushort* __restrict__ TOTAL, ushort* __restrict__ HB)
{
    int n0 = blockIdx.x * NPN;
    int c4 = threadIdx.x;
    const float4* W4 = (const float4*)Wce;
    float4 w0 = W4[0 * H4 + c4], w1 = W4[1 * H4 + c4], w2 = W4[2 * H4 + c4];
    float4 w3 = W4[3 * H4 + c4], w4 = W4[4 * H4 + c4], w5 = W4[5 * H4 + c4];
    float4 bb = ((const float4*)bc)[c4];
    float4 gg = ((const float4*)g)[c4], bo = ((const float4*)b)[c4];
    float4 mm = ((const float4*)m)[c4], vq = ((const float4*)vv)[c4];
    float4 sc;
    sc.x = gg.x * rsqrtf(vq.x + BNEPS); sc.y = gg.y * rsqrtf(vq.y + BNEPS);
    sc.z = gg.z * rsqrtf(vq.z + BNEPS); sc.w = gg.w * rsqrtf(vq.w + BNEPS);

    for (int u = 0; u < NPN; u++) {
        int n = n0 + u;
        if (n >= NATOMS) return;
        float4 p = unpack4(((const ushort4*)P)[(size_t)n * H4 + c4]);
        float4 acc;
        acc.x = fmaxf(p.x + bb.x, 0.f); acc.y = fmaxf(p.y + bb.y, 0.f);
        acc.z = fmaxf(p.z + bb.z, 0.f); acc.w = fmaxf(p.w + bb.w, 0.f);

        int lo = row_off[n], hi = row_off[n + 1];
        for (int j = lo; j < hi; j++) {
            int s = srcs[j];
            const float* e8 = eas + (size_t)j * 8;
            float4 eA = *(const float4*)(e8);
            float e4v = e8[4], e5v = e8[5];
            float4 ps = unpack4(((const ushort4*)P)[(size_t)s * H4 + c4]);
            float4 v;
            v.x = fmaxf(ps.x + eA.x * w0.x + eA.y * w1.x + eA.z * w2.x + eA.w * w3.x + e4v * w4.x + e5v * w5.x + bb.x, 0.f);
            v.y = fmaxf(ps.y + eA.x * w0.y + eA.y * w1.y + eA.z * w2.y + eA.w * w3.y + e4v * w4.y + e5v * w5.y + bb.y, 0.f);
            v.z = fmaxf(ps.z + eA.x * w0.z + eA.y * w1.z + eA.z * w2.z + eA.w * w3.z + e4v * w4.z + e5v * w5.z + bb.z, 0.f);
            v.w = fmaxf(ps.w + eA.x * w0.w + eA.y * w1.w + eA.z * w2.w + eA.w * w3.w + e4v * w4.w + e5v * w5.w + bb.w, 0.f);
            acc.x += v.x; acc.y += v.y; acc.z += v.z; acc.w += v.w;
        }

        float4 hv;
        hv.x = (acc.x - mm.x) * sc.x + bo.x;
        hv.y = (acc.y - mm.y) * sc.y + bo.y;
        hv.z = (acc.z - mm.z) * sc.z + bo.z;
        hv.w = (acc.w - mm.w) * sc.w + bo.w;
        size_t idx = (size_t)n * H4 + c4;
        float4 tt = unpack4(((const ushort4*)TOTAL)[idx]);
        tt.x += hv.x; tt.y += hv.y; tt.z += hv.z; tt.w += hv.w;
        ((ushort4*)TOTAL)[idx] = pack4(tt);
        ((ushort4*)HB)[idx] = pack4(hv);
    }
}

// ---------- per-graph pooling -> COMB bf16 [GPAD][2304] = [mean | add | max] ----------
// grid (NG, 3), 64 threads: each lane owns one c4 chunk
__global__ __launch_bounds__(64) void pool_k(const ushort* __restrict__ TOTAL,
                                             const int* __restrict__ bidx,
                                             ushort* __restrict__ COMB)
{
    int g = blockIdx.x;
    int c4 = blockIdx.y * 64 + threadIdx.x;
    ushort4* C4 = (ushort4*)COMB;
    int lo, hi;
    { int a = 0, b = NATOMS; while (a < b) { int mid = (a + b) >> 1; if (bidx[mid] < g) a = mid + 1; else b = mid; } lo = a; }
    { int a = lo, b = NATOMS; while (a < b) { int mid = (a + b) >> 1; if (bidx[mid] <= g) a = mid + 1; else b = mid; } hi = a; }
    int cnt = hi - lo;
    float4 sum = {0.f, 0.f, 0.f, 0.f};
    float4 mx = {-INFINITY, -INFINITY, -INFINITY, -INFINITY};
    for (int r = lo; r < hi; r++) {
        float4 v = unpack4(((const ushort4*)TOTAL)[(size_t)r * H4 + c4]);
        sum.x += v.x; sum.y += v.y; sum.z += v.z; sum.w += v.w;
        mx.x = fmaxf(mx.x, v.x); mx.y = fmaxf(mx.y, v.y);
        mx.z = fmaxf(mx.z, v.z); mx.w = fmaxf(mx.w, v.w);
    }
    float inv = 1.f / fmaxf((float)cnt, 1.f);
    if (cnt == 0) { mx.x = mx.y = mx.z = mx.w = 0.f; }
    float4 mean = {sum.x * inv, sum.y * inv, sum.z * inv, sum.w * inv};
    C4[(size_t)g * 576 + c4] = pack4(mean);
    C4[(size_t)g * 576 + 192 + c4] = pack4(sum);
    C4[(size_t)g * 576 + 384 + c4] = pack4(mx);
}

// ---------- last_hidden broadcast ----------
__global__ void bcast_k(const float* __restrict__ HS, float* __restrict__ out0)
{
    size_t idx = (size_t)blockIdx.x * 256 + threadIdx.x;   // over NG*LSEQ*H4
    int c4 = (int)(idx % H4);
    int g = (int)(idx / ((size_t)H4 * LSEQ));
    ((float4*)out0)[idx] = ((const float4*)HS)[(size_t)g * H4 + c4];
}

// ---------- recon gather ----------
__global__ void recon_k(const float* __restrict__ RG, const int* __restrict__ bidx,
                        float* __restrict__ out2)
{
    size_t idx = (size_t)blockIdx.x * 256 + threadIdx.x;   // over NATOMS*16
    int n = (int)(idx >> 4), c4 = (int)(idx & 15);
    ((float4*)out2)[idx] = ((const float4*)RG)[(size_t)bidx[n] * 16 + c4];
}

extern "C" void kernel_launch(void* const* d_in, const int* in_sizes, int n_in,
                              void* d_out, int out_size, void* d_ws, size_t ws_size,
                              hipStream_t stream)
{
    const float* x    = (const float*)d_in[0];
    const int*   ei   = (const int*)d_in[1];
    const float* ea   = (const float*)d_in[2];
    const int*   bidx = (const int*)d_in[3];
    const float* Win  = (const float*)d_in[5];
    const float* bin  = (const float*)d_in[6];
    const float* bn0g = (const float*)d_in[7];
    const float* bn0b = (const float*)d_in[8];
    const float* bn0m = (const float*)d_in[9];
    const float* bn0v = (const float*)d_in[10];
    const float* Wc   = (const float*)d_in[11];
    const float* bc   = (const float*)d_in[12];
    const float* bncg = (const float*)d_in[13];
    const float* bncb = (const float*)d_in[14];
    const float* bncm = (const float*)d_in[15];
    const float* bncv = (const float*)d_in[16];
    const float* Ws   = (const float*)d_in[17];
    const float* bs   = (const float*)d_in[18];
    const float* bnsg = (const float*)d_in[19];
    const float* bnsb = (const float*)d_in[20];
    const float* bnsm = (const float*)d_in[21];
    const float* bnsv = (const float*)d_in[22];
    const float* Wp   = (const float*)d_in[23];
    const float* bp   = (const float*)d_in[24];
    const float* Wd1  = (const float*)d_in[25];
    const float* bd1  = (const float*)d_in[26];
    const float* bndg = (const float*)d_in[27];
    const float* bndb = (const float*)d_in[28];
    const float* bndm = (const float*)d_in[29];
    const float* bndv = (const float*)d_in[30];
    const float* Wd2  = (const float*)d_in[31];
    const float* bd2  = (const float*)d_in[32];

    float* out  = (float*)d_out;
    float* out0 = out;
    float* out1 = out + (size_t)NG * LSEQ * HDIM;
    float* out2 = out1 + (size_t)NG * HDIM;

    char* w = (char*)d_ws;
    size_t off = 0;
    auto alloc = [&](size_t bytes) { void* p = w + off; off += (bytes + 255) & ~255ULL; return p; };
    ushort* P      = (ushort*)alloc((size_t)NPAD * HDIM * 2);     // 46.2 MB
    ushort* TOTAL  = (ushort*)alloc((size_t)NATOMS * HDIM * 2);   // 46.1 MB
    ushort* HB     = (ushort*)alloc((size_t)NPAD * HDIM * 2);     // 46.2 MB
    ushort* XB     = (ushort*)alloc((size_t)NPAD * 64 * 2);       // 3.9 MB
    ushort* WTc    = (ushort*)alloc((size_t)3 * 768 * 768 * 2);   // 3.5 MB
    ushort* WinT   = (ushort*)alloc((size_t)768 * 64 * 2);
    ushort* WsT    = (ushort*)alloc((size_t)768 * 2304 * 2);      // 3.5 MB
    ushort* WpT    = (ushort*)alloc((size_t)768 * 768 * 2);
    ushort* Wd1T   = (ushort*)alloc((size_t)768 * 768 * 2);
    ushort* Wd2T   = (ushort*)alloc((size_t)128 * 768 * 2);
    ushort* COMB   = (ushort*)alloc((size_t)GPAD * 2304 * 2);     // 3.0 MB
    float*  HS     = (float*) alloc((size_t)NG * HDIM * 4);
    ushort* HSB    = (ushort*)alloc((size_t)GPAD * HDIM * 2);
    ushort* POOLB  = (ushort*)alloc((size_t)GPAD * HDIM * 2);
    ushort* DGB    = (ushort*)alloc((size_t)GPAD * HDIM * 2);
    float*  RECONG = (float*) alloc((size_t)NG * 64 * 4);
    int*    cnt    = (int*)   alloc((size_t)NATOMS * 4);
    int*    row_off= (int*)   alloc((size_t)(NATOMS + 1) * 4);
    int*    cur    = (int*)   alloc((size_t)NATOMS * 4);
    int*    srcs   = (int*)   alloc((size_t)NEDGE * 4);
    float*  eas    = (float*) alloc((size_t)NEDGE * 8 * 4);       // 1.9 MB
    // peak ~163 MB

    const int* src_a = ei;
    const int* dst_a = ei + NEDGE;

    // 1 launch: all weight transposes + x cast + cnt zero
    prep_k<<<(int)((PC7 + 255) / 256), 256, 0, stream>>>(
        Wc, Win, Ws, Wp, Wd1, Wd2, x, WTc, WinT, WsT, WpT, Wd1T, Wd2T, XB, cnt);

    // CSR build
    count_k<<<(NEDGE + 255) / 256, 256, 0, stream>>>(dst_a, cnt);
    scan_k<<<1, 1024, 0, stream>>>(cnt, row_off, cur);
    fill_k<<<(NEDGE + 255) / 256, 256, 0, stream>>>(src_a, dst_a, ea, cur, srcs, eas);

    // input MLP via MFMA: h0 = BN(relu(x@Win+bin)) -> HB and TOTAL
    gemm_bt<1, 1><<<1410, 256, 0, stream>>>(
        XB, WinT, nullptr, HB, TOTAL, bin, bn0g, bn0b, bn0m, bn0v, NATOMS, HDIM, 64, 6);

    // 3 conv layers
    for (int i = 0; i < 3; i++) {
        const float* Wcei = Wc + (size_t)i * 774 * HDIM + (size_t)HDIM * HDIM;  // rows 768..773
        const float* bci  = bc + i * HDIM;
        gemm_bt<0, 1><<<1410, 256, 0, stream>>>(
            HB, WTc + (size_t)i * 768 * 768, nullptr, P, nullptr,
            nullptr, nullptr, nullptr, nullptr, nullptr, NATOMS, HDIM, HDIM, 6);
        node_agg_k<<<(NATOMS + NPN - 1) / NPN, 192, 0, stream>>>(
            P, row_off, srcs, eas, Wcei, bci,
            bncg + i * HDIM, bncb + i * HDIM, bncm + i * HDIM, bncv + i * HDIM, TOTAL, HB);
    }

    // pooling -> comb (bf16)
    pool_k<<<dim3(NG, 3), 64, 0, stream>>>(TOTAL, bidx, COMB);

    // hs = BN(relu(comb @ Ws + bs))
    gemm_bt<1, 0><<<dim3(6, 5), 256, 0, stream>>>(
        COMB, WsT, HS, HSB, nullptr, bs, bnsg, bnsb, bnsm, bnsv, NG, HDIM, 2304, 6);

    // last_hidden broadcast
    bcast_k<<<(NG * LSEQ * H4) / 256, 256, 0, stream>>>(HS, out0);

    // pooler = tanh(hs @ Wp + bp) -> out1
    gemm_bt<2, 0><<<dim3(6, 5), 256, 0, stream>>>(
        HSB, WpT, out1, POOLB, nullptr, bp, nullptr, nullptr, nullptr, nullptr, NG, HDIM, HDIM, 6);

    // dg = BN(relu(pooler @ Wd1 + bd1))
    gemm_bt<1, 0><<<dim3(6, 5), 256, 0, stream>>>(
        POOLB, Wd1T, nullptr, DGB, nullptr, bd1, bndg, bndb, bndm, bndv, NG, HDIM, HDIM, 6);

    // recon_g = dg @ Wd2 + bd2  (N=64)
    gemm_bt<3, 0><<<dim3(1, 5), 256, 0, stream>>>(
        DGB, Wd2T, RECONG, nullptr, nullptr, bd2, nullptr, nullptr, nullptr, nullptr, NG, 64, HDIM, 1);

    // expand recon to nodes
    recon_k<<<(NATOMS * 16) / 256, 256, 0, stream>>>(RECONG, bidx, out2);
}

// Round 9
// 668.118 us; speedup vs baseline: 3.9970x; 1.1551x over previous
//
#include <hip/hip_runtime.h>

#define NATOMS 30000
#define NPAD   30080        // 235*128
#define NEDGE  60000
#define HDIM   768
#define H4     192
#define NG     600
#define GPAD   640          // 5*128
#define LSEQ   20
#define BNEPS  1e-5f
#define KS     8            // split-K slices for tail GEMMs

typedef __attribute__((ext_vector_type(8))) short bf16x8;
typedef __attribute__((ext_vector_type(4))) float f32x4;

__device__ __forceinline__ ushort f2bf(float f) {
    union { float f; unsigned u; } v; v.f = f;
    unsigned r = v.u + 0x7FFFu + ((v.u >> 16) & 1u);
    return (ushort)(r >> 16);
}
__device__ __forceinline__ float bf2f(ushort u) {
    union { unsigned u; float f; } v; v.u = ((unsigned)u) << 16; return v.f;
}
__device__ __forceinline__ ushort4 pack4(float4 v) {
    ushort4 r; r.x = f2bf(v.x); r.y = f2bf(v.y); r.z = f2bf(v.z); r.w = f2bf(v.w); return r;
}
__device__ __forceinline__ float4 unpack4(ushort4 u) {
    float4 r; r.x = bf2f(u.x); r.y = bf2f(u.y); r.z = bf2f(u.z); r.w = bf2f(u.w); return r;
}
// async global->LDS, 16B per lane; LDS dest wave-uniform base + lane*16, global src per-lane
__device__ __forceinline__ void gl_lds16(const ushort* g, ushort* l) {
    __builtin_amdgcn_global_load_lds(
        (const __attribute__((address_space(1))) void*)(g),
        (__attribute__((address_space(3))) void*)(l), 16, 0, 0);
}

// ---------- fused prep: all weight transposes + x cast + cnt zero (1 launch) ----------
#define PC0 (3L*768*768)            // convT
#define PC1 (PC0 + 768L*64)         // WinT
#define PC2 (PC1 + 768L*2304)       // WsT
#define PC3 (PC2 + 768L*768)        // WpT
#define PC4 (PC3 + 768L*768)        // Wd1T
#define PC5 (PC4 + 128L*768)        // Wd2T
#define PC6 (PC5 + 480000L)         // XB (float4 units = NATOMS*64/4)
#define PC7 (PC6 + NATOMS)          // cnt zero
__global__ __launch_bounds__(256) void prep_k(
    const float* __restrict__ Wc, const float* __restrict__ Win, const float* __restrict__ Ws,
    const float* __restrict__ Wp, const float* __restrict__ Wd1, const float* __restrict__ Wd2,
    const float* __restrict__ x,
    ushort* __restrict__ WTc, ushort* __restrict__ WinT, ushort* __restrict__ WsT,
    ushort* __restrict__ WpT, ushort* __restrict__ Wd1T, ushort* __restrict__ Wd2T,
    ushort* __restrict__ XB, int* __restrict__ cnt)
{
    long idx = (long)blockIdx.x * 256 + threadIdx.x;
    if (idx < PC0) {
        long b = idx / (768 * 768), rem = idx % (768 * 768);
        long n = rem / 768, k = rem % 768;
        WTc[idx] = f2bf(Wc[b * 594432 + k * 768 + n]);          // Wc: [3][774][768]
    } else if (idx < PC1) {
        long j = idx - PC0; long n = j / 64, k = j % 64;
        WinT[j] = f2bf(Win[k * 768 + n]);
    } else if (idx < PC2) {
        long j = idx - PC1; long n = j / 2304, k = j % 2304;
        WsT[j] = f2bf(Ws[k * 768 + n]);
    } else if (idx < PC3) {
        long j = idx - PC2; long n = j / 768, k = j % 768;
        WpT[j] = f2bf(Wp[k * 768 + n]);
    } else if (idx < PC4) {
        long j = idx - PC3; long n = j / 768, k = j % 768;
        Wd1T[j] = f2bf(Wd1[k * 768 + n]);
    } else if (idx < PC5) {
        long j = idx - PC4; long n = j / 768, k = j % 768;
        Wd2T[j] = (n < 64) ? f2bf(Wd2[k * 64 + n]) : (ushort)0;  // Wd2: [768][64]
    } else if (idx < PC6) {
        long j = idx - PC5;
        ((ushort4*)XB)[j] = pack4(((const float4*)x)[j]);
    } else if (idx < PC7) {
        cnt[idx - PC6] = 0;
    }
}

// ---------- bf16 MFMA GEMM: 2-phase double-buffered global_load_lds staging ----------
// C = A[.][K] @ Bt[.][K]^T ; EPI: 0=none, 1=bias+relu+BN, 2=bias+tanh, 3=bias
// SWZ=1: 1-D grid, bcol-fast + bijective chunked XCD swizzle
template <int EPI, int SWZ>
__global__ __launch_bounds__(256) void gemm_bt(
    const ushort* __restrict__ A, const ushort* __restrict__ Bt,
    float* __restrict__ Cf, ushort* __restrict__ Cb, ushort* __restrict__ Cb2,
    const float* __restrict__ bias,
    const float* __restrict__ bng, const float* __restrict__ bnb,
    const float* __restrict__ bnm, const float* __restrict__ bnv,
    int Mreal, int Nreal, int K, int nbx)
{
    __shared__ ushort As[2][128 * 32];
    __shared__ ushort Bs[2][128 * 32];
    int t = threadIdx.x;
    int lane = t & 63, wave = t >> 6;
    int wr = wave >> 1, wc = wave & 1;
    int brow, bcol;
    if (SWZ) {
        int nwg = gridDim.x;
        int q = nwg >> 3, r = nwg & 7;
        int id = blockIdx.x;
        int xcd = id & 7, i = id >> 3;
        int s = (xcd < r) ? xcd * (q + 1) + i : r * (q + 1) + (xcd - r) * q + i;
        bcol = s % 6; brow = s / 6;           // SWZ path: nbx fixed = 6
    } else {
        bcol = blockIdx.x; brow = blockIdx.y;
    }

    f32x4 acc[4][4];
    #pragma unroll
    for (int i = 0; i < 4; i++)
        #pragma unroll
        for (int j = 0; j < 4; j++) acc[i][j] = (f32x4)0.f;

    // staging: wave w covers LDS chunks {2w,2w+1} of A and B (1 KB each)
    const int r0 = wave * 32 + (lane >> 2);
    const int ce = (lane & 3) * 8;
    const ushort* Ag0 = A + (size_t)(brow * 128 + r0) * K + ce;
    const ushort* Ag1 = A + (size_t)(brow * 128 + r0 + 16) * K + ce;
    const ushort* Bg0 = Bt + (size_t)(bcol * 128 + r0) * K + ce;
    const ushort* Bg1 = Bt + (size_t)(bcol * 128 + r0 + 16) * K + ce;
    const int wo = wave * 1024;

    const int lr = lane & 15, lk = (lane >> 4) * 8;

    // prologue: stage tile 0 into buf 0
    gl_lds16(Ag0, &As[0][wo]);
    gl_lds16(Ag1, &As[0][wo + 512]);
    gl_lds16(Bg0, &Bs[0][wo]);
    gl_lds16(Bg1, &Bs[0][wo + 512]);
    __syncthreads();

    int cur = 0;
    for (int kt = 0; kt < K; kt += 32) {
        if (kt + 32 < K) {
            int nb = cur ^ 1;
            gl_lds16(Ag0 + kt + 32, &As[nb][wo]);
            gl_lds16(Ag1 + kt + 32, &As[nb][wo + 512]);
            gl_lds16(Bg0 + kt + 32, &Bs[nb][wo]);
            gl_lds16(Bg1 + kt + 32, &Bs[nb][wo + 512]);
        }

        bf16x8 af[4], bfr[4];
        #pragma unroll
        for (int mf = 0; mf < 4; mf++)
            af[mf] = *(const bf16x8*)(&As[cur][(wr * 64 + mf * 16 + lr) * 32 + lk]);
        #pragma unroll
        for (int nf = 0; nf < 4; nf++)
            bfr[nf] = *(const bf16x8*)(&Bs[cur][(wc * 64 + nf * 16 + lr) * 32 + lk]);
        #pragma unroll
        for (int mf = 0; mf < 4; mf++)
            #pragma unroll
            for (int nf = 0; nf < 4; nf++)
                acc[mf][nf] = __builtin_amdgcn_mfma_f32_16x16x32_bf16(af[mf], bfr[nf], acc[mf][nf], 0, 0, 0);

        __syncthreads();
        cur ^= 1;
    }

    const int lq = lane >> 4;
    #pragma unroll
    for (int mf = 0; mf < 4; mf++) {
        #pragma unroll
        for (int nf = 0; nf < 4; nf++) {
            int col = bcol * 128 + wc * 64 + nf * 16 + lr;
            #pragma unroll
            for (int rg = 0; rg < 4; rg++) {
                int row = brow * 128 + wr * 64 + mf * 16 + lq * 4 + rg;
                if (row < Mreal && col < Nreal) {
                    float v = acc[mf][nf][rg];
                    if (EPI >= 1) v += bias[col];
                    if (EPI == 1) {
                        v = fmaxf(v, 0.f);
                        float s = bng[col] * rsqrtf(bnv[col] + BNEPS);
                        v = (v - bnm[col]) * s + bnb[col];
                    } else if (EPI == 2) {
                        v = tanhf(v);
                    }
                    size_t o = (size_t)row * Nreal + col;
                    if (Cf) Cf[o] = v;
                    if (Cb) Cb[o] = f2bf(v);
                    if (Cb2) Cb2[o] = f2bf(v);
                }
            }
        }
    }
}

// ---------- split-K partial GEMM for small-M tail GEMMs ----------
// grid (Nstr/128, 5, KS); CP[ks][640][Nstr] f32 partials; every element written each launch
__global__ __launch_bounds__(256) void gemm_pk(
    const ushort* __restrict__ A, const ushort* __restrict__ Bt,
    float* __restrict__ CP, int Nstr, int K)
{
    __shared__ ushort As[2][128 * 32];
    __shared__ ushort Bs[2][128 * 32];
    int t = threadIdx.x;
    int lane = t & 63, wave = t >> 6;
    int wr = wave >> 1, wc = wave & 1;
    int bcol = blockIdx.x, brow = blockIdx.y, ks = blockIdx.z;
    const int KL = K / KS;
    const int k0 = ks * KL, k1 = k0 + KL;

    f32x4 acc[4][4];
    #pragma unroll
    for (int i = 0; i < 4; i++)
        #pragma unroll
        for (int j = 0; j < 4; j++) acc[i][j] = (f32x4)0.f;

    const int r0 = wave * 32 + (lane >> 2);
    const int ce = (lane & 3) * 8;
    const ushort* Ag0 = A + (size_t)(brow * 128 + r0) * K + ce;
    const ushort* Ag1 = A + (size_t)(brow * 128 + r0 + 16) * K + ce;
    const ushort* Bg0 = Bt + (size_t)(bcol * 128 + r0) * K + ce;
    const ushort* Bg1 = Bt + (size_t)(bcol * 128 + r0 + 16) * K + ce;
    const int wo = wave * 1024;
    const int lr = lane & 15, lk = (lane >> 4) * 8;

    gl_lds16(Ag0 + k0, &As[0][wo]);
    gl_lds16(Ag1 + k0, &As[0][wo + 512]);
    gl_lds16(Bg0 + k0, &Bs[0][wo]);
    gl_lds16(Bg1 + k0, &Bs[0][wo + 512]);
    __syncthreads();

    int cur = 0;
    for (int kt = k0; kt < k1; kt += 32) {
        if (kt + 32 < k1) {
            int nb = cur ^ 1;
            gl_lds16(Ag0 + kt + 32, &As[nb][wo]);
            gl_lds16(Ag1 + kt + 32, &As[nb][wo + 512]);
            gl_lds16(Bg0 + kt + 32, &Bs[nb][wo]);
            gl_lds16(Bg1 + kt + 32, &Bs[nb][wo + 512]);
        }
        bf16x8 af[4], bfr[4];
        #pragma unroll
        for (int mf = 0; mf < 4; mf++)
            af[mf] = *(const bf16x8*)(&As[cur][(wr * 64 + mf * 16 + lr) * 32 + lk]);
        #pragma unroll
        for (int nf = 0; nf < 4; nf++)
            bfr[nf] = *(const bf16x8*)(&Bs[cur][(wc * 64 + nf * 16 + lr) * 32 + lk]);
        #pragma unroll
        for (int mf = 0; mf < 4; mf++)
            #pragma unroll
            for (int nf = 0; nf < 4; nf++)
                acc[mf][nf] = __builtin_amdgcn_mfma_f32_16x16x32_bf16(af[mf], bfr[nf], acc[mf][nf], 0, 0, 0);
        __syncthreads();
        cur ^= 1;
    }

    const int lq = lane >> 4;
    float* cp = CP + (size_t)ks * 640 * Nstr;
    #pragma unroll
    for (int mf = 0; mf < 4; mf++) {
        #pragma unroll
        for (int nf = 0; nf < 4; nf++) {
            int col = bcol * 128 + wc * 64 + nf * 16 + lr;
            #pragma unroll
            for (int rg = 0; rg < 4; rg++) {
                int row = brow * 128 + wr * 64 + mf * 16 + lq * 4 + rg;
                cp[(size_t)row * Nstr + col] = acc[mf][nf][rg];   // row<640, col<Nstr by grid
            }
        }
    }
}

// ---------- split-K epilogue: sum KS slices + bias/activation/BN + store ----------
// grid over NG * Nstr/4 threads (float4 per thread)
template <int EPI>
__global__ __launch_bounds__(256) void epi_k(
    const float* __restrict__ CP, int Nstr, int Nreal, int outStride,
    float* __restrict__ Cf, ushort* __restrict__ Cb,
    const float* __restrict__ bias,
    const float* __restrict__ bng, const float* __restrict__ bnb,
    const float* __restrict__ bnm, const float* __restrict__ bnv)
{
    int idx = blockIdx.x * 256 + threadIdx.x;
    int n4 = Nstr >> 2;
    int row = idx / n4, c4 = idx - row * n4;
    if (row >= NG) return;
    int col = c4 * 4;
    float4 s = {0.f, 0.f, 0.f, 0.f};
    #pragma unroll
    for (int ks = 0; ks < KS; ks++) {
        float4 p = *(const float4*)(CP + (size_t)ks * 640 * Nstr + (size_t)row * Nstr + col);
        s.x += p.x; s.y += p.y; s.z += p.z; s.w += p.w;
    }
    float v[4] = {s.x, s.y, s.z, s.w};
    #pragma unroll
    for (int j = 0; j < 4; j++) {
        int c = col + j;
        if (c >= Nreal) break;
        float u = v[j] + bias[c];
        if (EPI == 1) {
            u = fmaxf(u, 0.f);
            float sc = bng[c] * rsqrtf(bnv[c] + BNEPS);
            u = (u - bnm[c]) * sc + bnb[c];
        } else if (EPI == 2) {
            u = tanhf(u);
        }
        size_t o = (size_t)row * outStride + c;
        if (Cf) Cf[o] = u;
        if (Cb) Cb[o] = f2bf(u);
    }
}

// ================= CSR build (once; shared by all 3 conv layers) =================

__global__ void count_k(const int* __restrict__ dst_a, int* __restrict__ cnt)
{
    int e = blockIdx.x * 256 + threadIdx.x;
    if (e < NEDGE) atomicAdd(&cnt[dst_a[e]], 1);
}

__global__ __launch_bounds__(1024) void scan_k(const int* __restrict__ cnt,
                                               int* __restrict__ row_off,
                                               int* __restrict__ cur)
{
    __shared__ int part[1024];
    const int CH = (NATOMS + 1023) / 1024;
    int t = threadIdx.x;
    int base = t * CH;
    int s = 0;
    for (int i = base; i < base + CH && i < NATOMS; i++) s += cnt[i];
    part[t] = s;
    __syncthreads();
    for (int off = 1; off < 1024; off <<= 1) {
        int v = (t >= off) ? part[t - off] : 0;
        __syncthreads();
        part[t] += v;
        __syncthreads();
    }
    int excl = part[t] - s;
    for (int i = base; i < base + CH && i < NATOMS; i++) {
        row_off[i] = excl;
        cur[i] = excl;
        excl += cnt[i];
    }
    if (t == 1023) row_off[NATOMS] = part[1023];
}

__global__ void fill_k(const int* __restrict__ src_a, const int* __restrict__ dst_a,
                       const float* __restrict__ ea,
                       int* __restrict__ cur, int* __restrict__ srcs, float* __restrict__ eas)
{
    int e = blockIdx.x * 256 + threadIdx.x;
    if (e >= NEDGE) return;
    int d = dst_a[e];
    int pos = atomicAdd(&cur[d], 1);
    srcs[pos] = src_a[e];
    float* o = eas + (size_t)pos * 8;
    o[0] = ea[e * 6 + 0]; o[1] = ea[e * 6 + 1]; o[2] = ea[e * 6 + 2];
    o[3] = ea[e * 6 + 3]; o[4] = ea[e * 6 + 4]; o[5] = ea[e * 6 + 5];
}

// ---------- fused per-node aggregation (8 nodes/block): self-loop + edges + BN + TOTAL + HB ----------
#define NPN 8
__global__ __launch_bounds__(192) void node_agg_k(
    const ushort* __restrict__ P, const int* __restrict__ row_off,
    const int* __restrict__ srcs, const float* __restrict__ eas,
    const float* __restrict__ Wce, const float* __restrict__ bc,
    const float* __restrict__ g, const float* __restrict__ b,
    const float* __restrict__ m, const float* __restrict__ vv,
    ushort* __restrict__ TOTAL, ushort* __restrict__ HB)
{
    int n0 = blockIdx.x * NPN;
    int c4 = threadIdx.x;
    const float4* W4 = (const float4*)Wce;
    float4 w0 = W4[0 * H4 + c4], w1 = W4[1 * H4 + c4], w2 = W4[2 * H4 + c4];
    float4 w3 = W4[3 * H4 + c4], w4 = W4[4 * H4 + c4], w5 = W4[5 * H4 + c4];
    float4 bb = ((const float4*)bc)[c4];
    float4 gg = ((const float4*)g)[c4], bo = ((const float4*)b)[c4];
    float4 mm = ((const float4*)m)[c4], vq = ((const float4*)vv)[c4];
    float4 sc;
    sc.x = gg.x * rsqrtf(vq.x + BNEPS); sc.y = gg.y * rsqrtf(vq.y + BNEPS);
    sc.z = gg.z * rsqrtf(vq.z + BNEPS); sc.w = gg.w * rsqrtf(vq.w + BNEPS);

    for (int u = 0; u < NPN; u++) {
        int n = n0 + u;
        if (n >= NATOMS) return;
        float4 p = unpack4(((const ushort4*)P)[(size_t)n * H4 + c4]);
        float4 acc;
        acc.x = fmaxf(p.x + bb.x, 0.f); acc.y = fmaxf(p.y + bb.y, 0.f);
        acc.z = fmaxf(p.z + bb.z, 0.f); acc.w = fmaxf(p.w + bb.w, 0.f);

        int lo = row_off[n], hi = row_off[n + 1];
        for (int j = lo; j < hi; j++) {
            int s = srcs[j];
            const float* e8 = eas + (size_t)j * 8;
            float4 eA = *(const float4*)(e8);
            float e4v = e8[4], e5v = e8[5];
            float4 ps = unpack4(((const ushort4*)P)[(size_t)s * H4 + c4]);
            float4 v;
            v.x = fmaxf(ps.x + eA.x * w0.x + eA.y * w1.x + eA.z * w2.x + eA.w * w3.x + e4v * w4.x + e5v * w5.x + bb.x, 0.f);
            v.y = fmaxf(ps.y + eA.x * w0.y + eA.y * w1.y + eA.z * w2.y + eA.w * w3.y + e4v * w4.y + e5v * w5.y + bb.y, 0.f);
            v.z = fmaxf(ps.z + eA.x * w0.z + eA.y * w1.z + eA.z * w2.z + eA.w * w3.z + e4v * w4.z + e5v * w5.z + bb.z, 0.f);
            v.w = fmaxf(ps.w + eA.x * w0.w + eA.y * w1.w + eA.z * w2.w + eA.w * w3.w + e4v * w4.w + e5v * w5.w + bb.w, 0.f);
            acc.x += v.x; acc.y += v.y; acc.z += v.z; acc.w += v.w;
        }

        float4 hv;
        hv.x = (acc.x - mm.x) * sc.x + bo.x;
        hv.y = (acc.y - mm.y) * sc.y + bo.y;
        hv.z = (acc.z - mm.z) * sc.z + bo.z;
        hv.w = (acc.w - mm.w) * sc.w + bo.w;
        size_t idx = (size_t)n * H4 + c4;
        float4 tt = unpack4(((const ushort4*)TOTAL)[idx]);
        tt.x += hv.x; tt.y += hv.y; tt.z += hv.z; tt.w += hv.w;
        ((ushort4*)TOTAL)[idx] = pack4(tt);
        ((ushort4*)HB)[idx] = pack4(hv);
    }
}

// ---------- per-graph pooling -> COMB bf16 [GPAD][2304] = [mean | add | max] ----------
__global__ __launch_bounds__(64) void pool_k(const ushort* __restrict__ TOTAL,
                                             const int* __restrict__ bidx,
                                             ushort* __restrict__ COMB)
{
    int g = blockIdx.x;
    int c4 = blockIdx.y * 64 + threadIdx.x;
    ushort4* C4 = (ushort4*)COMB;
    int lo, hi;
    { int a = 0, b = NATOMS; while (a < b) { int mid = (a + b) >> 1; if (bidx[mid] < g) a = mid + 1; else b = mid; } lo = a; }
    { int a = lo, b = NATOMS; while (a < b) { int mid = (a + b) >> 1; if (bidx[mid] <= g) a = mid + 1; else b = mid; } hi = a; }
    int cnt = hi - lo;
    float4 sum = {0.f, 0.f, 0.f, 0.f};
    float4 mx = {-INFINITY, -INFINITY, -INFINITY, -INFINITY};
    for (int r = lo; r < hi; r++) {
        float4 v = unpack4(((const ushort4*)TOTAL)[(size_t)r * H4 + c4]);
        sum.x += v.x; sum.y += v.y; sum.z += v.z; sum.w += v.w;
        mx.x = fmaxf(mx.x, v.x); mx.y = fmaxf(mx.y, v.y);
        mx.z = fmaxf(mx.z, v.z); mx.w = fmaxf(mx.w, v.w);
    }
    float inv = 1.f / fmaxf((float)cnt, 1.f);
    if (cnt == 0) { mx.x = mx.y = mx.z = mx.w = 0.f; }
    float4 mean = {sum.x * inv, sum.y * inv, sum.z * inv, sum.w * inv};
    C4[(size_t)g * 576 + c4] = pack4(mean);
    C4[(size_t)g * 576 + 192 + c4] = pack4(sum);
    C4[(size_t)g * 576 + 384 + c4] = pack4(mx);
}

// ---------- last_hidden broadcast ----------
__global__ void bcast_k(const float* __restrict__ HS, float* __restrict__ out0)
{
    size_t idx = (size_t)blockIdx.x * 256 + threadIdx.x;   // over NG*LSEQ*H4
    int c4 = (int)(idx % H4);
    int g = (int)(idx / ((size_t)H4 * LSEQ));
    ((float4*)out0)[idx] = ((const float4*)HS)[(size_t)g * H4 + c4];
}

// ---------- recon gather ----------
__global__ void recon_k(const float* __restrict__ RG, const int* __restrict__ bidx,
                        float* __restrict__ out2)
{
    size_t idx = (size_t)blockIdx.x * 256 + threadIdx.x;   // over NATOMS*16
    int n = (int)(idx >> 4), c4 = (int)(idx & 15);
    ((float4*)out2)[idx] = ((const float4*)RG)[(size_t)bidx[n] * 16 + c4];
}

extern "C" void kernel_launch(void* const* d_in, const int* in_sizes, int n_in,
                              void* d_out, int out_size, void* d_ws, size_t ws_size,
                              hipStream_t stream)
{
    const float* x    = (const float*)d_in[0];
    const int*   ei   = (const int*)d_in[1];
    const float* ea   = (const float*)d_in[2];
    const int*   bidx = (const int*)d_in[3];
    const float* Win  = (const float*)d_in[5];
    const float* bin  = (const float*)d_in[6];
    const float* bn0g = (const float*)d_in[7];
    const float* bn0b = (const float*)d_in[8];
    const float* bn0m = (const float*)d_in[9];
    const float* bn0v = (const float*)d_in[10];
    const float* Wc   = (const float*)d_in[11];
    const float* bc   = (const float*)d_in[12];
    const float* bncg = (const float*)d_in[13];
    const float* bncb = (const float*)d_in[14];
    const float* bncm = (const float*)d_in[15];
    const float* bncv = (const float*)d_in[16];
    const float* Ws   = (const float*)d_in[17];
    const float* bs   = (const float*)d_in[18];
    const float* bnsg = (const float*)d_in[19];
    const float* bnsb = (const float*)d_in[20];
    const float* bnsm = (const float*)d_in[21];
    const float* bnsv = (const float*)d_in[22];
    const float* Wp   = (const float*)d_in[23];
    const float* bp   = (const float*)d_in[24];
    const float* Wd1  = (const float*)d_in[25];
    const float* bd1  = (const float*)d_in[26];
    const float* bndg = (const float*)d_in[27];
    const float* bndb = (const float*)d_in[28];
    const float* bndm = (const float*)d_in[29];
    const float* bndv = (const float*)d_in[30];
    const float* Wd2  = (const float*)d_in[31];
    const float* bd2  = (const float*)d_in[32];

    float* out  = (float*)d_out;
    float* out0 = out;
    float* out1 = out + (size_t)NG * LSEQ * HDIM;
    float* out2 = out1 + (size_t)NG * HDIM;

    char* w = (char*)d_ws;
    size_t off = 0;
    auto alloc = [&](size_t bytes) { void* p = w + off; off += (bytes + 255) & ~255ULL; return p; };
    ushort* P      = (ushort*)alloc((size_t)NPAD * HDIM * 2);     // 46.2 MB
    ushort* TOTAL  = (ushort*)alloc((size_t)NATOMS * HDIM * 2);   // 46.1 MB
    ushort* HB     = (ushort*)alloc((size_t)NPAD * HDIM * 2);     // 46.2 MB
    ushort* XB     = (ushort*)alloc((size_t)NPAD * 64 * 2);       // 3.9 MB
    ushort* WTc    = (ushort*)alloc((size_t)3 * 768 * 768 * 2);   // 3.5 MB
    ushort* WinT   = (ushort*)alloc((size_t)768 * 64 * 2);
    ushort* WsT    = (ushort*)alloc((size_t)768 * 2304 * 2);      // 3.5 MB
    ushort* WpT    = (ushort*)alloc((size_t)768 * 768 * 2);
    ushort* Wd1T   = (ushort*)alloc((size_t)768 * 768 * 2);
    ushort* Wd2T   = (ushort*)alloc((size_t)128 * 768 * 2);
    ushort* COMB   = (ushort*)alloc((size_t)GPAD * 2304 * 2);     // 3.0 MB
    float*  CP     = (float*) alloc((size_t)KS * 640 * 768 * 4);  // 15.7 MB
    float*  HS     = (float*) alloc((size_t)NG * HDIM * 4);
    ushort* HSB    = (ushort*)alloc((size_t)GPAD * HDIM * 2);
    ushort* POOLB  = (ushort*)alloc((size_t)GPAD * HDIM * 2);
    ushort* DGB    = (ushort*)alloc((size_t)GPAD * HDIM * 2);
    float*  RECONG = (float*) alloc((size_t)NG * 64 * 4);
    int*    cnt    = (int*)   alloc((size_t)NATOMS * 4);
    int*    row_off= (int*)   alloc((size_t)(NATOMS + 1) * 4);
    int*    cur    = (int*)   alloc((size_t)NATOMS * 4);
    int*    srcs   = (int*)   alloc((size_t)NEDGE * 4);
    float*  eas    = (float*) alloc((size_t)NEDGE * 8 * 4);       // 1.9 MB
    // peak ~180 MB

    const int* src_a = ei;
    const int* dst_a = ei + NEDGE;

    // 1 launch: all weight transposes + x cast + cnt zero
    prep_k<<<(int)((PC7 + 255) / 256), 256, 0, stream>>>(
        Wc, Win, Ws, Wp, Wd1, Wd2, x, WTc, WinT, WsT, WpT, Wd1T, Wd2T, XB, cnt);

    // CSR build
    count_k<<<(NEDGE + 255) / 256, 256, 0, stream>>>(dst_a, cnt);
    scan_k<<<1, 1024, 0, stream>>>(cnt, row_off, cur);
    fill_k<<<(NEDGE + 255) / 256, 256, 0, stream>>>(src_a, dst_a, ea, cur, srcs, eas);

    // input MLP via MFMA: h0 = BN(relu(x@Win+bin)) -> HB and TOTAL
    gemm_bt<1, 1><<<1410, 256, 0, stream>>>(
        XB, WinT, nullptr, HB, TOTAL, bin, bn0g, bn0b, bn0m, bn0v, NATOMS, HDIM, 64, 6);

    // 3 conv layers
    for (int i = 0; i < 3; i++) {
        const float* Wcei = Wc + (size_t)i * 774 * HDIM + (size_t)HDIM * HDIM;  // rows 768..773
        const float* bci  = bc + i * HDIM;
        gemm_bt<0, 1><<<1410, 256, 0, stream>>>(
            HB, WTc + (size_t)i * 768 * 768, nullptr, P, nullptr,
            nullptr, nullptr, nullptr, nullptr, nullptr, NATOMS, HDIM, HDIM, 6);
        node_agg_k<<<(NATOMS + NPN - 1) / NPN, 192, 0, stream>>>(
            P, row_off, srcs, eas, Wcei, bci,
            bncg + i * HDIM, bncb + i * HDIM, bncm + i * HDIM, bncv + i * HDIM, TOTAL, HB);
    }

    // pooling -> comb (bf16)
    pool_k<<<dim3(NG, 3), 64, 0, stream>>>(TOTAL, bidx, COMB);

    // hs = BN(relu(comb @ Ws + bs)) — split-K
    gemm_pk<<<dim3(6, 5, KS), 256, 0, stream>>>(COMB, WsT, CP, 768, 2304);
    epi_k<1><<<(NG * 192 + 255) / 256, 256, 0, stream>>>(
        CP, 768, 768, 768, HS, HSB, bs, bnsg, bnsb, bnsm, bnsv);

    // last_hidden broadcast
    bcast_k<<<(NG * LSEQ * H4) / 256, 256, 0, stream>>>(HS, out0);

    // pooler = tanh(hs @ Wp + bp) -> out1 — split-K
    gemm_pk<<<dim3(6, 5, KS), 256, 0, stream>>>(HSB, WpT, CP, 768, 768);
    epi_k<2><<<(NG * 192 + 255) / 256, 256, 0, stream>>>(
        CP, 768, 768, 768, out1, POOLB, bp, nullptr, nullptr, nullptr, nullptr);

    // dg = BN(relu(pooler @ Wd1 + bd1)) — split-K
    gemm_pk<<<dim3(6, 5, KS), 256, 0, stream>>>(POOLB, Wd1T, CP, 768, 768);
    epi_k<1><<<(NG * 192 + 255) / 256, 256, 0, stream>>>(
        CP, 768, 768, 768, nullptr, DGB, bd1, bndg, bndb, bndm, bndv);

    // recon_g = dg @ Wd2 + bd2  (N=64, Nstr=128) — split-K
    gemm_pk<<<dim3(1, 5, KS), 256, 0, stream>>>(DGB, Wd2T, CP, 128, 768);
    epi_k<3><<<(NG * 32 + 255) / 256, 256, 0, stream>>>(
        CP, 128, 64, 64, RECONG, nullptr, bd2, nullptr, nullptr, nullptr, nullptr);

    // expand recon to nodes
    recon_k<<<(NATOMS * 16) / 256, 256, 0, stream>>>(RECONG, bidx, out2);
}